// Round 3
// baseline (10000.824 us; speedup 1.0000x reference)
//
#include <hip/hip_runtime.h>

#define IMH 512
#define IMW 512
#define NB 4
#define NPIX (IMH*IMW)
#define NITER 100

#define TX 64
#define TY 32
#define GXT (IMW/TX)         // 8
#define GYT (IMH/TY)         // 16
#define NBLK (GXT*GYT*NB)    // 512

#define PH (TY+6)   // 38  p state, halo 3
#define PW (TX+6)   // 70
#define VH (TY+4)   // 36  v state (halo 2) and r temp
#define VW (TX+4)   // 68
#define QH (TY+2)   // 34  p_new temp, halo 1
#define QW (TX+2)   // 66

__device__ __forceinline__ float shrink01(float d) {
  return d > 0.1f ? d - 0.1f : (d < -0.1f ? d + 0.1f : 0.f);
}

// ginv = 1 + gx^2 + gy^2 ; also zero set-A state arrays and flags
__global__ __launch_bounds__(256) void init_kernel(
    const float* __restrict__ f, float* __restrict__ ginv,
    float* __restrict__ z1, float* __restrict__ z2, float* __restrict__ z3,
    int* __restrict__ flags) {
  int idx0 = blockIdx.x * blockDim.x + threadIdx.x;
  if (idx0 < NBLK) flags[idx0] = 0;
  int total = NB * NPIX;
  for (int idx = idx0; idx < total; idx += gridDim.x * blockDim.x) {
    int b = idx / NPIX;
    int rem = idx - b * NPIX;
    int y = rem / IMW, x = rem - y * IMW;
    const float* fb = f + (size_t)b * NPIX;
    auto ld = [&](int yy, int xx) -> float {
      if (yy < 0 || yy >= IMH || xx < 0 || xx >= IMW) return 0.f;
      return fb[yy * IMW + xx];
    };
    float a00 = ld(y-1,x-1), a01 = ld(y-1,x), a02 = ld(y-1,x+1);
    float a10 = ld(y,  x-1),                  a12 = ld(y,  x+1);
    float a20 = ld(y+1,x-1), a21 = ld(y+1,x), a22 = ld(y+1,x+1);
    float gx = (a02 - a00) + 2.f*(a12 - a10) + (a22 - a20);
    float gy = (a20 - a00) + 2.f*(a21 - a01) + (a22 - a02);
    ginv[idx] = 1.f + gx*gx + gy*gy;
    z1[idx] = 0.f; z2[idx] = 0.f; z3[idx] = 0.f;
  }
}

__global__ __launch_bounds__(256, 2) void persist_kernel(
    const float* __restrict__ f, const float* __restrict__ ginv,
    float* __restrict__ p1A, float* __restrict__ p2A, float* __restrict__ vA,
    float* __restrict__ p1B, float* __restrict__ p2B, float* __restrict__ vB,
    float* __restrict__ uout, int* flags) {
  __shared__ float P1s[PH*PW], P2s[PH*PW];   // p state, halo 3
  __shared__ float Vs[VH*VW];                // v state, halo 2
  __shared__ float Rs[VH*VW];                // r temp / vnew staging
  __shared__ float Q1[QH*QW], Q2[QH*QW];     // p_new temp, halo 1

  const int tid = threadIdx.x;
  // XCD-chunked bijective swizzle: each XCD gets 64 consecutive virt blocks
  int phys = blockIdx.x;
  int virt = (phys & 7) * (NBLK >> 3) + (phys >> 3);
  const int bx  = virt & (GXT - 1);
  const int byy = (virt >> 3) & (GYT - 1);
  const int b   = virt >> 7;          // / (GXT*GYT)
  const int x0 = bx * TX, y0 = byy * TY;
  const size_t boff = (size_t)b * NPIX;
  const float* fb = f + boff;
  const float* gb = ginv + boff;

  // neighbor flag index for tid<8 (8-connected, same batch)
  int nbr = -1;
  if (tid < 8) {
    int dy = tid < 3 ? -1 : (tid > 4 ? 1 : 0);
    int dx;
    if (tid < 3) dx = tid - 1;
    else if (tid == 3) dx = -1;
    else if (tid == 4) dx = 1;
    else dx = tid - 6;
    int nx = bx + dx, ny = byy + dy;
    if (nx >= 0 && nx < GXT && ny >= 0 && ny < GYT)
      nbr = b * (GXT * GYT) + ny * GXT + nx;
  }

  // zero LDS state (matches p=v=0 initial condition)
  for (int i = tid; i < PH*PW; i += 256) { P1s[i] = 0.f; P2s[i] = 0.f; }
  for (int i = tid; i < VH*VW; i += 256) { Vs[i] = 0.f; }
  __syncthreads();

  for (int j = 1; j <= NITER; ++j) {
    const float* gp1i = (j & 1) ? p1A : p1B;   // read set[(j-1)&1]
    const float* gp2i = (j & 1) ? p2A : p2B;
    const float* gvi  = (j & 1) ? vA  : vB;
    float* gp1o = (j & 1) ? p1B : p1A;         // write set[j&1]
    float* gp2o = (j & 1) ? p2B : p2A;
    float* gvo  = (j & 1) ? vB  : vA;

    // wait: all existing neighbors have published iteration j-1
    if (j > 1 && nbr >= 0) {
      while (__hip_atomic_load(&flags[nbr], __ATOMIC_RELAXED,
                               __HIP_MEMORY_SCOPE_AGENT) < j - 1)
        __builtin_amdgcn_s_sleep(2);
    }
    __syncthreads();
    __threadfence();   // acquire: invalidate stale cached rim data

    // (a) refresh halo rings from global
    // p rings depth 1..3 outside owned: 612 cells
    for (int i = tid; i < 612; i += 256) {
      int py, px;
      if (i < 210)      { py = i / 70;            px = i % 70; }
      else if (i < 420) { int k = i - 210; py = 35 + k / 70; px = k % 70; }
      else              { int k = i - 420; py = 3 + k / 6; int c = k % 6;
                          px = c < 3 ? c : 64 + c; }
      int gy = y0 + py - 3, gx = x0 + px - 3;
      float a = 0.f, c2 = 0.f;
      if (gy >= 0 && gy < IMH && gx >= 0 && gx < IMW) {
        size_t o = boff + (size_t)gy * IMW + gx;
        a = gp1i[o]; c2 = gp2i[o];
      }
      P1s[py*PW + px] = a; P2s[py*PW + px] = c2;
    }
    // v rings depth 1..2: 400 cells
    for (int i = tid; i < 400; i += 256) {
      int vy, vx;
      if (i < 136)      { vy = i / 68;            vx = i % 68; }
      else if (i < 272) { int k = i - 136; vy = 34 + k / 68; vx = k % 68; }
      else              { int k = i - 272; vy = 2 + k / 4; int c = k % 4;
                          vx = c < 2 ? c : 64 + c; }
      int gy = y0 + vy - 2, gx = x0 + vx - 2;
      float d = 0.f;
      if (gy >= 0 && gy < IMH && gx >= 0 && gx < IMW)
        d = gvi[boff + (size_t)gy * IMW + gx];
      Vs[vy*VW + vx] = d;
    }
    __syncthreads();

    // (c) r = div(p) - f + v over halo-2
    for (int i = tid; i < VH*VW; i += 256) {
      int vy = i / VW, vx = i - vy * VW;
      int gy = y0 + vy - 2, gx = x0 + vx - 2;
      float val = 0.f;
      if (gy >= 0 && gy < IMH && gx >= 0 && gx < IMW) {
        int pc = (vy+1)*PW + (vx+1);
        float divp = (P1s[pc+1] - P1s[pc-1]) + (P2s[pc+PW] - P2s[pc-PW]);
        val = divp - fb[(size_t)gy*IMW + gx] + Vs[i];
      }
      Rs[i] = val;
    }
    __syncthreads();

    // (e) p_new over halo-1
    for (int i = tid; i < QH*QW; i += 256) {
      int qy = i / QW, qx = i - qy * QW;
      int gy = y0 + qy - 1, gx = x0 + qx - 1;
      float n1 = 0.f, n2 = 0.f;
      if (gy >= 0 && gy < IMH && gx >= 0 && gx < IMW) {
        int c = (qy+1)*VW + (qx+1);
        float rgx = ((Rs[c-VW+1] - Rs[c-VW-1]) + 2.f*(Rs[c+1] - Rs[c-1])
                   + (Rs[c+VW+1] - Rs[c+VW-1])) * 0.125f;
        float rgy = ((Rs[c+VW-1] - Rs[c-VW-1]) + 2.f*(Rs[c+VW] - Rs[c-VW])
                   + (Rs[c+VW+1] - Rs[c-VW+1])) * 0.125f;
        float gg = gb[(size_t)gy*IMW + gx];
        float denom = 1.f + 0.125f * __builtin_amdgcn_sqrtf(rgx*rgx + rgy*rgy) * gg;
        float inv = __builtin_amdgcn_rcpf(denom);
        int pc = (qy+2)*PW + (qx+2);
        n1 = (P1s[pc] + 0.125f*rgx) * inv;
        n2 = (P2s[pc] + 0.125f*rgy) * inv;
      }
      Q1[i] = n1; Q2[i] = n2;
    }
    __syncthreads();

    // (g) owned tile: div(p_new) + v update (or u on last iter)
    if (j == NITER) {
      for (int i = tid; i < TY*TX; i += 256) {
        int ty = i / TX, tx = i - ty * TX;
        int qc = (ty+1)*QW + (tx+1);
        float divp = (Q1[qc+1] - Q1[qc-1]) + (Q2[qc+QW] - Q2[qc-QW]);
        float vold = Vs[(ty+2)*VW + (tx+2)];
        size_t o = (size_t)(y0+ty)*IMW + (x0+tx);
        uout[boff + o] = fb[o] - vold - divp;
      }
    } else {
      for (int i = tid; i < TY*TX; i += 256) {
        int ty = i / TX, tx = i - ty * TX;
        int qc = (ty+1)*QW + (tx+1);
        float divp = (Q1[qc+1] - Q1[qc-1]) + (Q2[qc+QW] - Q2[qc-QW]);
        int vc = (ty+2)*VW + (tx+2);
        Rs[vc] = shrink01(Vs[vc] + divp);   // vnew staged (Rs dead)
      }
      __syncthreads();

      // (i) commit LDS state + publish rims to global
      for (int i = tid; i < TY*TX; i += 256) {
        int ty = i / TX, tx = i - ty * TX;
        int qc = (ty+1)*QW + (tx+1);
        P1s[(ty+3)*PW + (tx+3)] = Q1[qc];
        P2s[(ty+3)*PW + (tx+3)] = Q2[qc];
        Vs[(ty+2)*VW + (tx+2)] = Rs[(ty+2)*VW + (tx+2)];
      }
      // p rim depth 1..3 of owned: 540 cells
      for (int i = tid; i < 540; i += 256) {
        int oy, ox;
        if (i < 192)      { oy = i / 64;            ox = i % 64; }
        else if (i < 384) { int k = i - 192; oy = 29 + k / 64; ox = k % 64; }
        else              { int k = i - 384; oy = 3 + k / 6; int c = k % 6;
                            ox = c < 3 ? c : 58 + c; }
        size_t o = boff + (size_t)(y0+oy)*IMW + (x0+ox);
        gp1o[o] = Q1[(oy+1)*QW + (ox+1)];
        gp2o[o] = Q2[(oy+1)*QW + (ox+1)];
      }
      // v rim depth 1..2 of owned: 368 cells
      for (int i = tid; i < 368; i += 256) {
        int oy, ox;
        if (i < 128)      { oy = i / 64;            ox = i % 64; }
        else if (i < 256) { int k = i - 128; oy = 30 + k / 64; ox = k % 64; }
        else              { int k = i - 256; oy = 2 + k / 4; int c = k % 4;
                            ox = c < 2 ? c : 60 + c; }
        gvo[boff + (size_t)(y0+oy)*IMW + (x0+ox)] = Rs[(oy+2)*VW + (ox+2)];
      }
      __threadfence();   // release: flush rim writes
      __syncthreads();
      if (tid == 0)
        __hip_atomic_store(&flags[virt], j, __ATOMIC_RELEASE,
                           __HIP_MEMORY_SCOPE_AGENT);
    }
  }
}

extern "C" void kernel_launch(void* const* d_in, const int* in_sizes, int n_in,
                              void* d_out, int out_size, void* d_ws, size_t ws_size,
                              hipStream_t stream) {
  const float* f = (const float*)d_in[0];
  float* u = (float*)d_out;
  float* ws = (float*)d_ws;
  const size_t N = (size_t)NB * NPIX;
  // ws: ginv, p1A, p2A, vA, p1B, p2B, vB (7 x 4MB) + flags
  float* g   = ws + 0*N;
  float* p1a = ws + 1*N;
  float* p2a = ws + 2*N;
  float* va  = ws + 3*N;
  float* p1b = ws + 4*N;
  float* p2b = ws + 5*N;
  float* vb  = ws + 6*N;
  int* flags = (int*)(ws + 7*N);

  init_kernel<<<1024, 256, 0, stream>>>(f, g, p1a, p2a, va, flags);

  void* args[] = { (void*)&f, (void*)&g,
                   (void*)&p1a, (void*)&p2a, (void*)&va,
                   (void*)&p1b, (void*)&p2b, (void*)&vb,
                   (void*)&u, (void*)&flags };
  hipLaunchCooperativeKernel((const void*)persist_kernel,
                             dim3(NBLK), dim3(256), args, 0, stream);
}

// Round 4
// 690.810 us; speedup vs baseline: 14.4770x; 14.4770x over previous
//
#include <hip/hip_runtime.h>

#define IMH 512
#define IMW 512
#define NB 4
#define NPIX (IMH*IMW)

#define TX 64
#define TY 16
#define GXT 8                 // IMW/TX
#define GYT 32                // IMH/TY
#define NBLK (GXT*GYT*NB)     // 1024

// k=2 fusion ladder (halos): p0@5, v0@4 -> r1@4 -> p1@3 -> {v1,r2}@2 -> p2@1 -> out@0
// All x-origins 4-aligned; staged arrays have x-halo 8 so LDS f4 reads need no clamping.
#define PW 80
#define P_H 26   // p staged: y [-5,21), x [-8,72)
#define VW 80
#define V_H 24   // v staged: y [-4,20), x [-8,72)
#define RW 72
#define R_H 24   // r: y [-4,20), x [-4,68)
#define BW 72
#define B_H 22   // p1: y [-3,19), x [-4,68)
#define EW 72
#define E_H 20   // v1: y [-2,18), x [-4,68)

__device__ __forceinline__ float4 lds4(const float* p, int i){ return *(const float4*)(p + i); }
__device__ __forceinline__ void  sts4(float* p, int i, float4 v){ *(float4*)(p + i) = v; }
__device__ __forceinline__ float4 f4zero(){ return make_float4(0.f,0.f,0.f,0.f); }
__device__ __forceinline__ float shrink01(float d){
  return d - fminf(fmaxf(d, -0.1f), 0.1f);   // v_med3 idiom
}

template<bool EDGE>
__device__ __forceinline__ float4 gld4(const float* base, int gy, int gx){
  if (EDGE){ gy = min(max(gy,0),IMH-1); gx = min(max(gx,0),IMW-4); }
  return *(const float4*)(base + gy*IMW + gx);
}
__device__ __forceinline__ float4 mask4(float4 v, int gy, int gx){
  if ((unsigned)gy >= (unsigned)IMH) return f4zero();
  v.x = ((unsigned)(gx+0) < (unsigned)IMW) ? v.x : 0.f;
  v.y = ((unsigned)(gx+1) < (unsigned)IMW) ? v.y : 0.f;
  v.z = ((unsigned)(gx+2) < (unsigned)IMW) ? v.z : 0.f;
  v.w = ((unsigned)(gx+3) < (unsigned)IMW) ? v.w : 0.f;
  return v;
}

// 3x3 Sobel/8 on LDS array Rsb (stride RW) around chunk at index rc (col = x+4).
__device__ __forceinline__ void sobel_rg(const float* Rsb, int rc, int col,
                                         float4& rgx, float4& rgy){
  int lo = (col == 0) ? 0 : -4;        // clamped reads feed junk cells only
  int ro = (col == RW-4) ? 0 : 4;
  float4 l0 = lds4(Rsb, rc-RW+lo), m0 = lds4(Rsb, rc-RW), r0 = lds4(Rsb, rc-RW+ro);
  float4 l1 = lds4(Rsb, rc   +lo), m1 = lds4(Rsb, rc   ), r1 = lds4(Rsb, rc   +ro);
  float4 l2 = lds4(Rsb, rc+RW+lo), m2 = lds4(Rsb, rc+RW), r2 = lds4(Rsb, rc+RW+ro);
  float d0x = m0.y - l0.w, d1x = m0.z - m0.x, d2x = m0.w - m0.y, d3x = r0.x - m0.z;
  float d0y = m1.y - l1.w, d1y = m1.z - m1.x, d2y = m1.w - m1.y, d3y = r1.x - m1.z;
  float d0z = m2.y - l2.w, d1z = m2.z - m2.x, d2z = m2.w - m2.y, d3z = r2.x - m2.z;
  rgx.x = (d0x + 2.f*d0y + d0z) * 0.125f;
  rgx.y = (d1x + 2.f*d1y + d1z) * 0.125f;
  rgx.z = (d2x + 2.f*d2y + d2z) * 0.125f;
  rgx.w = (d3x + 2.f*d3y + d3z) * 0.125f;
  float cm1 = l2.w - l0.w;
  float c0 = m2.x - m0.x, c1 = m2.y - m0.y, c2 = m2.z - m0.z, c3 = m2.w - m0.w;
  float c4 = r2.x - r0.x;
  rgy.x = (cm1 + 2.f*c0 + c1) * 0.125f;
  rgy.y = (c0  + 2.f*c1 + c2) * 0.125f;
  rgy.z = (c1  + 2.f*c2 + c3) * 0.125f;
  rgy.w = (c2  + 2.f*c3 + c4) * 0.125f;
}

template<bool EDGE>
__device__ __forceinline__ void p_update(const float* Rsb, const float* Pa, const float* Pb,
    int rc, int col, int pidx, const float* gbase, int gy, int gx,
    float4& n1, float4& n2){
  float4 rgx, rgy; sobel_rg(Rsb, rc, col, rgx, rgy);
  float4 pa = lds4(Pa, pidx), pb = lds4(Pb, pidx);
  float4 gg = gld4<EDGE>(gbase, gy, gx);
#define PE(c) { \
    float mag = __builtin_amdgcn_sqrtf(rgx.c*rgx.c + rgy.c*rgy.c); \
    float inv = __builtin_amdgcn_rcpf(1.f + 0.125f*mag*gg.c); \
    n1.c = (pa.c + 0.125f*rgx.c)*inv; n2.c = (pb.c + 0.125f*rgy.c)*inv; }
  PE(x) PE(y) PE(z) PE(w)
#undef PE
}

template<bool FIRST, bool LAST, bool EDGE>
__device__ __forceinline__ void iter_body(
    const float* fb, const float* gb,
    const float* p1b, const float* p2b, const float* vb,
    float* p1o, float* p2o, float* vo, float* uo,
    int x0, int y0, int tid,
    float* P1s, float* P2s, float* Vs, float* Rs,
    float* B1s, float* B2s, float* Es)
{
  // ---- stage p (halo 5) and v (halo 4)
  for (unsigned i = tid; i < 20u*P_H; i += 256){
    int cy = i / 20u, cx = i - cy*20;
    int x = cx*4 - 8, y = cy - 5;
    float4 a, b;
    if (FIRST){ a = f4zero(); b = f4zero(); }
    else {
      int gy = y0+y, gx = x0+x;
      a = gld4<EDGE>(p1b, gy, gx); b = gld4<EDGE>(p2b, gy, gx);
      if (EDGE){ a = mask4(a,gy,gx); b = mask4(b,gy,gx); }
    }
    int idx = (y+5)*PW + (x+8);
    sts4(P1s, idx, a); sts4(P2s, idx, b);
  }
  for (unsigned i = tid; i < 20u*V_H; i += 256){
    int cy = i / 20u, cx = i - cy*20;
    int x = cx*4 - 8, y = cy - 4;
    float4 v;
    if (FIRST) v = f4zero();
    else {
      int gy = y0+y, gx = x0+x;
      v = gld4<EDGE>(vb, gy, gx);
      if (EDGE) v = mask4(v, gy, gx);
    }
    sts4(Vs, (y+4)*VW + (x+8), v);
  }
  __syncthreads();

  // ---- r1 = div(p) - f + v  over halo-4
  for (unsigned i = tid; i < 18u*R_H; i += 256){
    int cy = i / 18u, cx = i - cy*18;
    int x = cx*4 - 4, y = cy - 4;
    int pc = (y+5)*PW + (x+8);
    float4 o = lds4(P1s,pc), l = lds4(P1s,pc-4), r = lds4(P1s,pc+4);
    float4 up = lds4(P2s,pc-PW), dn = lds4(P2s,pc+PW);
    float4 vv = lds4(Vs,(y+4)*VW + (x+8));
    float4 ff = gld4<EDGE>(fb, y0+y, x0+x);
    float4 rv;
    rv.x = (o.y - l.w) + (dn.x - up.x) - ff.x + vv.x;
    rv.y = (o.z - o.x) + (dn.y - up.y) - ff.y + vv.y;
    rv.z = (o.w - o.y) + (dn.z - up.z) - ff.z + vv.z;
    rv.w = (r.x - o.z) + (dn.w - up.w) - ff.w + vv.w;
    if (EDGE) rv = mask4(rv, y0+y, x0+x);
    sts4(Rs, (y+4)*RW + (x+4), rv);
  }
  __syncthreads();

  // ---- p1 over halo-3
  for (unsigned i = tid; i < 18u*B_H; i += 256){
    int cy = i / 18u, cx = i - cy*18;
    int x = cx*4 - 4, y = cy - 3;
    float4 n1, n2;
    p_update<EDGE>(Rs, P1s, P2s, (y+4)*RW+(x+4), x+4, (y+5)*PW+(x+8),
                   gb, y0+y, x0+x, n1, n2);
    if (EDGE){ n1 = mask4(n1, y0+y, x0+x); n2 = mask4(n2, y0+y, x0+x); }
    int bi = (y+3)*BW + (x+4);
    sts4(B1s, bi, n1); sts4(B2s, bi, n2);
  }
  __syncthreads();

  // ---- v1 = shrink(v + div p1); r2 = div p1 - f + v1  over halo-2
  for (unsigned i = tid; i < 18u*E_H; i += 256){
    int cy = i / 18u, cx = i - cy*18;
    int x = cx*4 - 4, y = cy - 2;
    int bc = (y+3)*BW + (x+4);
    int col = x+4;
    int lo = (col==0)?0:-4, ro = (col==BW-4)?0:4;
    float4 o = lds4(B1s,bc), l = lds4(B1s,bc+lo), r = lds4(B1s,bc+ro);
    float4 up = lds4(B2s,bc-BW), dn = lds4(B2s,bc+BW);
    float4 vv = lds4(Vs,(y+4)*VW+(x+8));
    float4 ff = gld4<EDGE>(fb, y0+y, x0+x);
    float4 db, vn, r2v;
    db.x = (o.y - l.w) + (dn.x - up.x);
    db.y = (o.z - o.x) + (dn.y - up.y);
    db.z = (o.w - o.y) + (dn.z - up.z);
    db.w = (r.x - o.z) + (dn.w - up.w);
    vn.x = shrink01(vv.x + db.x); vn.y = shrink01(vv.y + db.y);
    vn.z = shrink01(vv.z + db.z); vn.w = shrink01(vv.w + db.w);
    r2v.x = db.x - ff.x + vn.x; r2v.y = db.y - ff.y + vn.y;
    r2v.z = db.z - ff.z + vn.z; r2v.w = db.w - ff.w + vn.w;
    if (EDGE){ vn = mask4(vn, y0+y, x0+x); r2v = mask4(r2v, y0+y, x0+x); }
    sts4(Es, (y+2)*EW + (x+4), vn);
    sts4(Rs, (y+4)*RW + (x+4), r2v);   // overwrite r1 (dead)
  }
  __syncthreads();

  // ---- p2 over halo-1 (stored into P buffers, p_old dead)
  for (unsigned i = tid; i < 18u*18u; i += 256){
    int cy = i / 18u, cx = i - cy*18;
    int x = cx*4 - 4, y = cy - 1;
    float4 n1, n2;
    p_update<EDGE>(Rs, B1s, B2s, (y+4)*RW+(x+4), x+4, (y+3)*BW+(x+4),
                   gb, y0+y, x0+x, n1, n2);
    if (EDGE){ n1 = mask4(n1,y0+y,x0+x); n2 = mask4(n2,y0+y,x0+x); }
    int qi = (y+1)*PW + (x+8);
    sts4(P1s, qi, n1); sts4(P2s, qi, n2);
  }
  __syncthreads();

  // ---- outputs over owned tile (exactly 256 chunks, one per thread)
  {
    int cx = tid & 15, cy = tid >> 4;
    int x = cx*4, y = cy;
    int qc = (y+1)*PW + (x+8);
    float4 o = lds4(P1s,qc), l = lds4(P1s,qc-4), r = lds4(P1s,qc+4);
    float4 up = lds4(P2s,qc-PW), dn = lds4(P2s,qc+PW);
    float4 dq;
    dq.x = (o.y - l.w) + (dn.x - up.x);
    dq.y = (o.z - o.x) + (dn.y - up.y);
    dq.z = (o.w - o.y) + (dn.z - up.z);
    dq.w = (r.x - o.z) + (dn.w - up.w);
    float4 vv = lds4(Es,(y+2)*EW+(x+4));   // v1
    size_t go = (size_t)(y0+y)*IMW + (x0+x);
    if (LAST){
      float4 ff = gld4<false>(fb, y0+y, x0+x);
      float4 uu;
      uu.x = ff.x - vv.x - dq.x; uu.y = ff.y - vv.y - dq.y;
      uu.z = ff.z - vv.z - dq.z; uu.w = ff.w - vv.w - dq.w;
      *(float4*)(uo + go) = uu;
    } else {
      float4 o2 = lds4(P2s,qc);
      float4 vnew;
      vnew.x = shrink01(vv.x + dq.x); vnew.y = shrink01(vv.y + dq.y);
      vnew.z = shrink01(vv.z + dq.z); vnew.w = shrink01(vv.w + dq.w);
      *(float4*)(p1o + go) = o;
      *(float4*)(p2o + go) = o2;
      *(float4*)(vo  + go) = vnew;
    }
  }
}

template<bool FIRST, bool LAST>
__global__ __launch_bounds__(256, 3) void iter2_kernel(
    const float* __restrict__ f, const float* __restrict__ ginv,
    const float* __restrict__ p1in, const float* __restrict__ p2in,
    const float* __restrict__ vin,
    float* __restrict__ p1out, float* __restrict__ p2out,
    float* __restrict__ vout, float* __restrict__ uout)
{
  __shared__ alignas(16) float P1s[P_H*PW], P2s[P_H*PW];
  __shared__ alignas(16) float Vs[V_H*VW], Rs[R_H*RW];
  __shared__ alignas(16) float B1s[B_H*BW], B2s[B_H*BW];
  __shared__ alignas(16) float Es[E_H*EW];

  int phys = blockIdx.x;
  int virt = (phys & 7) * (NBLK/8) + (phys >> 3);   // XCD-chunked, bijective
  int bx = virt & (GXT-1);
  int by = (virt >> 3) & (GYT-1);
  int b  = virt >> 8;
  int x0 = bx*TX, y0 = by*TY;
  size_t boff = (size_t)b * NPIX;
  bool edge = (bx==0) | (bx==GXT-1) | (by==0) | (by==GYT-1);
  int tid = threadIdx.x;

  if (edge)
    iter_body<FIRST,LAST,true>(f+boff, ginv+boff, p1in+boff, p2in+boff, vin+boff,
        p1out+boff, p2out+boff, vout+boff, uout+boff, x0, y0, tid,
        P1s, P2s, Vs, Rs, B1s, B2s, Es);
  else
    iter_body<FIRST,LAST,false>(f+boff, ginv+boff, p1in+boff, p2in+boff, vin+boff,
        p1out+boff, p2out+boff, vout+boff, uout+boff, x0, y0, tid,
        P1s, P2s, Vs, Rs, B1s, B2s, Es);
}

// ginv = 1 + gx^2 + gy^2, vectorized: one f4 chunk per thread
__global__ __launch_bounds__(256) void init_kernel(
    const float* __restrict__ f, float* __restrict__ ginv) {
  int i = blockIdx.x * 256 + threadIdx.x;       // 262144 chunks total
  int b = i >> 16; int rem = i & 0xFFFF;
  int gy = rem >> 7; int gx = (rem & 127) * 4;
  const float* fb = f + (size_t)b * NPIX;
  float L[3], R[3]; float4 O[3];
  for (int k = 0; k < 3; ++k){
    int y = gy + k - 1;
    if ((unsigned)y < (unsigned)IMH){
      const float* rp = fb + (size_t)y*IMW + gx;
      O[k] = *(const float4*)rp;
      L[k] = (gx > 0) ? rp[-1] : 0.f;
      R[k] = (gx < IMW-4) ? rp[4] : 0.f;
    } else { O[k] = f4zero(); L[k] = 0.f; R[k] = 0.f; }
  }
  float4 out;
#define GE(c, im1, i0, ip1) { \
    float sx = (i0##_p - i0##_m)*2.f + (im1##_p - im1##_m) + (ip1##_p - ip1##_m); \
    float sy = (ip1##_m - im1##_m) + 2.f*(ip1##_c - im1##_c) + (ip1##_p - im1##_p); \
    out.c = 1.f + sx*sx + sy*sy; }
  { // element 0: cols -1,0,1
    float a_m=L[0], a_c=O[0].x, a_p=O[0].y;
    float b_m=L[1], b_c=O[1].x, b_p=O[1].y;
    float c_m=L[2], c_c=O[2].x, c_p=O[2].y;
    GE(x, a, b, c)
  }
  { float a_m=O[0].x, a_c=O[0].y, a_p=O[0].z;
    float b_m=O[1].x, b_c=O[1].y, b_p=O[1].z;
    float c_m=O[2].x, c_c=O[2].y, c_p=O[2].z;
    GE(y, a, b, c) }
  { float a_m=O[0].y, a_c=O[0].z, a_p=O[0].w;
    float b_m=O[1].y, b_c=O[1].z, b_p=O[1].w;
    float c_m=O[2].y, c_c=O[2].z, c_p=O[2].w;
    GE(z, a, b, c) }
  { float a_m=O[0].z, a_c=O[0].w, a_p=R[0];
    float b_m=O[1].z, b_c=O[1].w, b_p=R[1];
    float c_m=O[2].z, c_c=O[2].w, c_p=R[2];
    GE(w, a, b, c) }
#undef GE
  *(float4*)(ginv + (size_t)b*NPIX + (size_t)gy*IMW + gx) = out;
}

extern "C" void kernel_launch(void* const* d_in, const int* in_sizes, int n_in,
                              void* d_out, int out_size, void* d_ws, size_t ws_size,
                              hipStream_t stream) {
  const float* f = (const float*)d_in[0];
  float* u = (float*)d_out;
  float* ws = (float*)d_ws;
  const size_t N = (size_t)NB * NPIX;
  float* g   = ws + 0*N;
  float* p1a = ws + 1*N;
  float* p2a = ws + 2*N;
  float* va  = ws + 3*N;
  float* p1b = ws + 4*N;
  float* p2b = ws + 5*N;
  float* vb  = ws + 6*N;

  init_kernel<<<1024, 256, 0, stream>>>(f, g);

  for (int l = 0; l < 50; ++l) {
    const float *pi1, *pi2, *vi;
    float *po1, *po2, *vo;
    if ((l & 1) == 0) { pi1 = p1a; pi2 = p2a; vi = va; po1 = p1b; po2 = p2b; vo = vb; }
    else              { pi1 = p1b; pi2 = p2b; vi = vb; po1 = p1a; po2 = p2a; vo = va; }
    if (l == 0)
      iter2_kernel<true, false><<<NBLK, 256, 0, stream>>>(f, g, pi1, pi2, vi, po1, po2, vo, u);
    else if (l == 49)
      iter2_kernel<false, true><<<NBLK, 256, 0, stream>>>(f, g, pi1, pi2, vi, po1, po2, vo, u);
    else
      iter2_kernel<false, false><<<NBLK, 256, 0, stream>>>(f, g, pi1, pi2, vi, po1, po2, vo, u);
  }
}

// Round 5
// 628.870 us; speedup vs baseline: 15.9028x; 1.0985x over previous
//
#include <hip/hip_runtime.h>

#define IMH 512
#define IMW 512
#define NB 4
#define NPIX (IMH*IMW)

#define TX 64
#define TY 32
#define GXT 8                 // IMW/TX
#define GYT 16                // IMH/TY
#define NBLK (GXT*GYT*NB)     // 512  == 2 blocks/CU exactly

// k=2 fusion, in-place state:
// P (p, halo5, y[-5,37) x[-8,72))  holds p_old -> p1 -> p2
// V (v, halo4, y[-4,36) x[-4,68))  holds v_old -> v1
// R (r, halo4, same layout as V)   holds r1 -> r2
#define PW 80
#define P_H 42
#define VW 72
#define V_H 40
#define RW 72

#define PIDX(y,x) (((y)+5)*PW + ((x)+8))
#define VIDX(y,x) (((y)+4)*VW + ((x)+4))

__device__ __forceinline__ float4 lds4(const float* p, int i){ return *(const float4*)(p + i); }
__device__ __forceinline__ void  sts4(float* p, int i, float4 v){ *(float4*)(p + i) = v; }
__device__ __forceinline__ float4 f4zero(){ return make_float4(0.f,0.f,0.f,0.f); }
__device__ __forceinline__ float shrink01(float d){
  return d - fminf(fmaxf(d, -0.1f), 0.1f);   // v_med3 idiom
}

template<bool EDGE>
__device__ __forceinline__ float4 gld4(const float* base, int gy, int gx){
  if (EDGE){ gy = min(max(gy,0),IMH-1); gx = min(max(gx,0),IMW-4); }
  return *(const float4*)(base + gy*IMW + gx);
}
__device__ __forceinline__ float4 mask4(float4 v, int gy, int gx){
  if ((unsigned)gy >= (unsigned)IMH) return f4zero();
  v.x = ((unsigned)(gx+0) < (unsigned)IMW) ? v.x : 0.f;
  v.y = ((unsigned)(gx+1) < (unsigned)IMW) ? v.y : 0.f;
  v.z = ((unsigned)(gx+2) < (unsigned)IMW) ? v.z : 0.f;
  v.w = ((unsigned)(gx+3) < (unsigned)IMW) ? v.w : 0.f;
  return v;
}

struct Row { float4 l, m, r; };
__device__ __forceinline__ Row load_row(const float* A, int base, int lo, int ro){
  Row q; q.l = lds4(A, base+lo); q.m = lds4(A, base); q.r = lds4(A, base+ro);
  return q;
}
__device__ __forceinline__ float4 dxv(const Row& q){
  return make_float4(q.m.y-q.l.w, q.m.z-q.m.x, q.m.w-q.m.y, q.r.x-q.m.z);
}
// Sobel/8 gradients at center row B from rows A(above), B, C(below)
__device__ __forceinline__ void sobel_rows(const Row& A, const Row& B, const Row& C,
                                           float4& rgx, float4& rgy){
  float4 da = dxv(A), db = dxv(B), dc = dxv(C);
  rgx.x = (da.x + 2.f*db.x + dc.x) * 0.125f;
  rgx.y = (da.y + 2.f*db.y + dc.y) * 0.125f;
  rgx.z = (da.z + 2.f*db.z + dc.z) * 0.125f;
  rgx.w = (da.w + 2.f*db.w + dc.w) * 0.125f;
  float cm1 = C.l.w - A.l.w;
  float c0 = C.m.x - A.m.x, c1 = C.m.y - A.m.y;
  float c2 = C.m.z - A.m.z, c3 = C.m.w - A.m.w;
  float c4 = C.r.x - A.r.x;
  rgy.x = (cm1 + 2.f*c0 + c1) * 0.125f;
  rgy.y = (c0  + 2.f*c1 + c2) * 0.125f;
  rgy.z = (c1  + 2.f*c2 + c3) * 0.125f;
  rgy.w = (c2  + 2.f*c3 + c4) * 0.125f;
}
__device__ __forceinline__ void p_elem(float4 rgx, float4 rgy, float4 pa, float4 pb,
                                       float4 gg, float4& n1, float4& n2){
#define PE(c) { \
    float mag = __builtin_amdgcn_sqrtf(rgx.c*rgx.c + rgy.c*rgy.c); \
    float inv = __builtin_amdgcn_rcpf(1.f + 0.125f*mag*gg.c); \
    n1.c = (pa.c + 0.125f*rgx.c)*inv; n2.c = (pb.c + 0.125f*rgy.c)*inv; }
  PE(x) PE(y) PE(z) PE(w)
#undef PE
}

// paired-row p-update, in place on P1s/P2s, reading sobel of Rs
template<bool EDGE>
__device__ __forceinline__ void p_phase(const float* Rs, float* P1s, float* P2s,
    const float* gb, int x0, int y0, int tid, int ylo, int npairs){
  int total = npairs * 18;
  for (int i = tid; i < total; i += 256){
    int pr = i / 18, cx = i - pr*18;
    int x = cx*4 - 4;
    int y = ylo + pr*2;
    int col = x + 4;
    int lo = (col==0) ? 0 : -4;          // clamped reads feed junk cells only
    int ro = (col==RW-4) ? 0 : 4;
    int base = VIDX(y,x);
    Row Rm1 = load_row(Rs, base-RW,   lo, ro);
    Row R0  = load_row(Rs, base,      lo, ro);
    Row R1  = load_row(Rs, base+RW,   lo, ro);
    Row R2  = load_row(Rs, base+2*RW, lo, ro);
    float4 rgx0, rgy0, rgx1, rgy1;
    sobel_rows(Rm1, R0, R1, rgx0, rgy0);
    sobel_rows(R0,  R1, R2, rgx1, rgy1);
    int p0 = PIDX(y,x), p1i = p0 + PW;
    float4 pa0 = lds4(P1s,p0),  pb0 = lds4(P2s,p0);
    float4 pa1 = lds4(P1s,p1i), pb1 = lds4(P2s,p1i);
    float4 g0 = gld4<EDGE>(gb, y0+y,   x0+x);
    float4 g1 = gld4<EDGE>(gb, y0+y+1, x0+x);
    float4 n10,n20,n11,n21;
    p_elem(rgx0,rgy0,pa0,pb0,g0,n10,n20);
    p_elem(rgx1,rgy1,pa1,pb1,g1,n11,n21);
    if (EDGE){
      n10 = mask4(n10, y0+y,   x0+x); n20 = mask4(n20, y0+y,   x0+x);
      n11 = mask4(n11, y0+y+1, x0+x); n21 = mask4(n21, y0+y+1, x0+x);
    }
    sts4(P1s,p0,n10);  sts4(P2s,p0,n20);
    sts4(P1s,p1i,n11); sts4(P2s,p1i,n21);
  }
}

template<bool FIRST, bool LAST, bool EDGE>
__device__ __forceinline__ void iter_body(
    const float* fb, const float* gb,
    const float* p1b, const float* p2b, const float* vb,
    float* p1o, float* p2o, float* vo, float* uo,
    int x0, int y0, int tid,
    float* P1s, float* P2s, float* Vs, float* Rs)
{
  // ---- stage p (halo 5) and v (halo 4)
  for (int i = tid; i < 42*20; i += 256){
    int cy = i / 20, cx = i - cy*20;
    int x = cx*4 - 8, y = cy - 5;
    float4 a, b;
    if (FIRST){ a = f4zero(); b = f4zero(); }
    else {
      int gy = y0+y, gx = x0+x;
      a = gld4<EDGE>(p1b, gy, gx); b = gld4<EDGE>(p2b, gy, gx);
      if (EDGE){ a = mask4(a,gy,gx); b = mask4(b,gy,gx); }
    }
    int idx = PIDX(y,x);
    sts4(P1s, idx, a); sts4(P2s, idx, b);
  }
  for (int i = tid; i < 40*18; i += 256){
    int cy = i / 18, cx = i - cy*18;
    int x = cx*4 - 4, y = cy - 4;
    float4 v;
    if (FIRST) v = f4zero();
    else {
      int gy = y0+y, gx = x0+x;
      v = gld4<EDGE>(vb, gy, gx);
      if (EDGE) v = mask4(v, gy, gx);
    }
    sts4(Vs, VIDX(y,x), v);
  }
  __syncthreads();

  // ---- r1 = div(p) - f + v  over halo-4 (40 rows x 18 chunks)
  for (int i = tid; i < 40*18; i += 256){
    int cy = i / 18, cx = i - cy*18;
    int x = cx*4 - 4, y = cy - 4;
    int pc = PIDX(y,x);
    float4 o = lds4(P1s,pc), l = lds4(P1s,pc-4), r = lds4(P1s,pc+4);
    float4 up = lds4(P2s,pc-PW), dn = lds4(P2s,pc+PW);
    float4 vv = lds4(Vs, VIDX(y,x));
    float4 ff = gld4<EDGE>(fb, y0+y, x0+x);
    float4 rv;
    rv.x = (o.y - l.w) + (dn.x - up.x) - ff.x + vv.x;
    rv.y = (o.z - o.x) + (dn.y - up.y) - ff.y + vv.y;
    rv.z = (o.w - o.y) + (dn.z - up.z) - ff.z + vv.z;
    rv.w = (r.x - o.z) + (dn.w - up.w) - ff.w + vv.w;
    if (EDGE) rv = mask4(rv, y0+y, x0+x);
    sts4(Rs, VIDX(y,x), rv);
  }
  __syncthreads();

  // ---- p1 over halo-3 (38 rows = 19 pairs), in place on P
  p_phase<EDGE>(Rs, P1s, P2s, gb, x0, y0, tid, -3, 19);
  __syncthreads();

  // ---- v1 = shrink(v + div p1) in place on V; r2 = div p1 - f + v1 -> Rs  (36 rows)
  for (int i = tid; i < 36*18; i += 256){
    int cy = i / 18, cx = i - cy*18;
    int x = cx*4 - 4, y = cy - 2;
    int pc = PIDX(y,x);
    float4 o = lds4(P1s,pc), l = lds4(P1s,pc-4), r = lds4(P1s,pc+4);
    float4 up = lds4(P2s,pc-PW), dn = lds4(P2s,pc+PW);
    float4 vv = lds4(Vs, VIDX(y,x));
    float4 ff = gld4<EDGE>(fb, y0+y, x0+x);
    float4 db, vn, r2v;
    db.x = (o.y - l.w) + (dn.x - up.x);
    db.y = (o.z - o.x) + (dn.y - up.y);
    db.z = (o.w - o.y) + (dn.z - up.z);
    db.w = (r.x - o.z) + (dn.w - up.w);
    vn.x = shrink01(vv.x + db.x); vn.y = shrink01(vv.y + db.y);
    vn.z = shrink01(vv.z + db.z); vn.w = shrink01(vv.w + db.w);
    r2v.x = db.x - ff.x + vn.x; r2v.y = db.y - ff.y + vn.y;
    r2v.z = db.z - ff.z + vn.z; r2v.w = db.w - ff.w + vn.w;
    if (EDGE){ vn = mask4(vn, y0+y, x0+x); r2v = mask4(r2v, y0+y, x0+x); }
    sts4(Vs, VIDX(y,x), vn);
    sts4(Rs, VIDX(y,x), r2v);
  }
  __syncthreads();

  // ---- p2 over halo-1 (34 rows = 17 pairs), in place on P
  p_phase<EDGE>(Rs, P1s, P2s, gb, x0, y0, tid, -1, 17);
  __syncthreads();

  // ---- outputs over owned tile (512 chunks)
  for (int i = tid; i < 32*16; i += 256){
    int cy = i >> 4, cx = i & 15;
    int x = cx*4, y = cy;
    int pc = PIDX(y,x);
    float4 o = lds4(P1s,pc), l = lds4(P1s,pc-4), r = lds4(P1s,pc+4);
    float4 up = lds4(P2s,pc-PW), dn = lds4(P2s,pc+PW);
    float4 dq;
    dq.x = (o.y - l.w) + (dn.x - up.x);
    dq.y = (o.z - o.x) + (dn.y - up.y);
    dq.z = (o.w - o.y) + (dn.z - up.z);
    dq.w = (r.x - o.z) + (dn.w - up.w);
    float4 vv = lds4(Vs, VIDX(y,x));   // v1
    size_t go = (size_t)(y0+y)*IMW + (x0+x);
    if (LAST){
      float4 ff = gld4<false>(fb, y0+y, x0+x);
      float4 uu;
      uu.x = ff.x - vv.x - dq.x; uu.y = ff.y - vv.y - dq.y;
      uu.z = ff.z - vv.z - dq.z; uu.w = ff.w - vv.w - dq.w;
      *(float4*)(uo + go) = uu;
    } else {
      float4 o2 = lds4(P2s,pc);
      float4 vnew;
      vnew.x = shrink01(vv.x + dq.x); vnew.y = shrink01(vv.y + dq.y);
      vnew.z = shrink01(vv.z + dq.z); vnew.w = shrink01(vv.w + dq.w);
      *(float4*)(p1o + go) = o;
      *(float4*)(p2o + go) = o2;
      *(float4*)(vo  + go) = vnew;
    }
  }
}

template<bool FIRST, bool LAST>
__global__ __launch_bounds__(256, 2) void iter2_kernel(
    const float* __restrict__ f, const float* __restrict__ ginv,
    const float* __restrict__ p1in, const float* __restrict__ p2in,
    const float* __restrict__ vin,
    float* __restrict__ p1out, float* __restrict__ p2out,
    float* __restrict__ vout, float* __restrict__ uout)
{
  __shared__ alignas(16) float P1s[P_H*PW], P2s[P_H*PW];
  __shared__ alignas(16) float Vs[V_H*VW], Rs[V_H*RW];

  int phys = blockIdx.x;
  int virt = (phys & 7) * (NBLK/8) + (phys >> 3);   // XCD-chunked, bijective
  int bx = virt & (GXT-1);
  int by = (virt >> 3) & (GYT-1);
  int b  = virt >> 7;
  int x0 = bx*TX, y0 = by*TY;
  size_t boff = (size_t)b * NPIX;
  bool edge = (bx==0) | (bx==GXT-1) | (by==0) | (by==GYT-1);
  int tid = threadIdx.x;

  if (edge)
    iter_body<FIRST,LAST,true>(f+boff, ginv+boff, p1in+boff, p2in+boff, vin+boff,
        p1out+boff, p2out+boff, vout+boff, uout+boff, x0, y0, tid,
        P1s, P2s, Vs, Rs);
  else
    iter_body<FIRST,LAST,false>(f+boff, ginv+boff, p1in+boff, p2in+boff, vin+boff,
        p1out+boff, p2out+boff, vout+boff, uout+boff, x0, y0, tid,
        P1s, P2s, Vs, Rs);
}

// ginv = 1 + gx^2 + gy^2, vectorized: one f4 chunk per thread
__global__ __launch_bounds__(256) void init_kernel(
    const float* __restrict__ f, float* __restrict__ ginv) {
  int i = blockIdx.x * 256 + threadIdx.x;       // 262144 chunks total
  int b = i >> 16; int rem = i & 0xFFFF;
  int gy = rem >> 7; int gx = (rem & 127) * 4;
  const float* fb = f + (size_t)b * NPIX;
  float L[3], R[3]; float4 O[3];
  for (int k = 0; k < 3; ++k){
    int y = gy + k - 1;
    if ((unsigned)y < (unsigned)IMH){
      const float* rp = fb + (size_t)y*IMW + gx;
      O[k] = *(const float4*)rp;
      L[k] = (gx > 0) ? rp[-1] : 0.f;
      R[k] = (gx < IMW-4) ? rp[4] : 0.f;
    } else { O[k] = f4zero(); L[k] = 0.f; R[k] = 0.f; }
  }
  float4 out;
#define GE(c, im1, i0, ip1) { \
    float sx = (i0##_p - i0##_m)*2.f + (im1##_p - im1##_m) + (ip1##_p - ip1##_m); \
    float sy = (ip1##_m - im1##_m) + 2.f*(ip1##_c - im1##_c) + (ip1##_p - im1##_p); \
    out.c = 1.f + sx*sx + sy*sy; }
  { float a_m=L[0], a_c=O[0].x, a_p=O[0].y;
    float b_m=L[1], b_c=O[1].x, b_p=O[1].y;
    float c_m=L[2], c_c=O[2].x, c_p=O[2].y;
    GE(x, a, b, c) }
  { float a_m=O[0].x, a_c=O[0].y, a_p=O[0].z;
    float b_m=O[1].x, b_c=O[1].y, b_p=O[1].z;
    float c_m=O[2].x, c_c=O[2].y, c_p=O[2].z;
    GE(y, a, b, c) }
  { float a_m=O[0].y, a_c=O[0].z, a_p=O[0].w;
    float b_m=O[1].y, b_c=O[1].z, b_p=O[1].w;
    float c_m=O[2].y, c_c=O[2].z, c_p=O[2].w;
    GE(z, a, b, c) }
  { float a_m=O[0].z, a_c=O[0].w, a_p=R[0];
    float b_m=O[1].z, b_c=O[1].w, b_p=R[1];
    float c_m=O[2].z, c_c=O[2].w, c_p=R[2];
    GE(w, a, b, c) }
#undef GE
  *(float4*)(ginv + (size_t)b*NPIX + (size_t)gy*IMW + gx) = out;
}

extern "C" void kernel_launch(void* const* d_in, const int* in_sizes, int n_in,
                              void* d_out, int out_size, void* d_ws, size_t ws_size,
                              hipStream_t stream) {
  const float* f = (const float*)d_in[0];
  float* u = (float*)d_out;
  float* ws = (float*)d_ws;
  const size_t N = (size_t)NB * NPIX;
  float* g   = ws + 0*N;
  float* p1a = ws + 1*N;
  float* p2a = ws + 2*N;
  float* va  = ws + 3*N;
  float* p1b = ws + 4*N;
  float* p2b = ws + 5*N;
  float* vb  = ws + 6*N;

  init_kernel<<<1024, 256, 0, stream>>>(f, g);

  for (int l = 0; l < 50; ++l) {
    const float *pi1, *pi2, *vi;
    float *po1, *po2, *vo;
    if ((l & 1) == 0) { pi1 = p1a; pi2 = p2a; vi = va; po1 = p1b; po2 = p2b; vo = vb; }
    else              { pi1 = p1b; pi2 = p2b; vi = vb; po1 = p1a; po2 = p2a; vo = va; }
    if (l == 0)
      iter2_kernel<true, false><<<NBLK, 256, 0, stream>>>(f, g, pi1, pi2, vi, po1, po2, vo, u);
    else if (l == 49)
      iter2_kernel<false, true><<<NBLK, 256, 0, stream>>>(f, g, pi1, pi2, vi, po1, po2, vo, u);
    else
      iter2_kernel<false, false><<<NBLK, 256, 0, stream>>>(f, g, pi1, pi2, vi, po1, po2, vo, u);
  }
}

// Round 6
// 458.331 us; speedup vs baseline: 21.8201x; 1.3721x over previous
//
#include <hip/hip_runtime.h>

#define IMH 512
#define IMW 512
#define NB 4
#define NPIX (IMH*IMW)

#define TX 64
#define TY 32
#define GXT 8                 // IMW/TX
#define GYT 16                // IMH/TY
#define NBLK (GXT*GYT*NB)     // 512  == 2 blocks/CU exactly
#define NTH 512               // 8 waves/block -> 16 waves/CU

// k=4 fusion, in-place LDS state (ladder: p0@9,v0@8 -> r1@8 -> p1@7 -> {v1,r2}@6
//  -> p2@5 -> {v2,r3}@4 -> p3@3 -> {v3,r4}@2 -> p4@1 -> out@0):
// P (p): y in [-9,41) = 50 rows, x in [-12,76) stride 88   (holds p0->p1->p2->p3->p4)
// V (v): y in [-8,40) = 48 rows, x in [-8,72)  stride 80   (holds v0->v1->v2->v3)
// R (r): same dims as V                                     (holds r1->r2->r3->r4)
// Total LDS = (50*88*2 + 48*80*2)*4 = 65,920 B -> 2 blocks/CU on 160 KiB.
#define PW2 88
#define P_H2 50
#define VW2 80
#define V_H2 48

#define PIDX(y,x) (((y)+9)*PW2 + ((x)+12))
#define VIDX(y,x) (((y)+8)*VW2 + ((x)+8))

__device__ __forceinline__ float4 lds4(const float* p, int i){ return *(const float4*)(p + i); }
__device__ __forceinline__ void  sts4(float* p, int i, float4 v){ *(float4*)(p + i) = v; }
__device__ __forceinline__ float4 f4zero(){ return make_float4(0.f,0.f,0.f,0.f); }
__device__ __forceinline__ float shrink01(float d){
  return d - fminf(fmaxf(d, -0.1f), 0.1f);   // v_med3 idiom
}

template<bool EDGE>
__device__ __forceinline__ float4 gld4(const float* base, int gy, int gx){
  if (EDGE){ gy = min(max(gy,0),IMH-1); gx = min(max(gx,0),IMW-4); }
  return *(const float4*)(base + gy*IMW + gx);
}
__device__ __forceinline__ float4 mask4(float4 v, int gy, int gx){
  if ((unsigned)gy >= (unsigned)IMH) return f4zero();
  v.x = ((unsigned)(gx+0) < (unsigned)IMW) ? v.x : 0.f;
  v.y = ((unsigned)(gx+1) < (unsigned)IMW) ? v.y : 0.f;
  v.z = ((unsigned)(gx+2) < (unsigned)IMW) ? v.z : 0.f;
  v.w = ((unsigned)(gx+3) < (unsigned)IMW) ? v.w : 0.f;
  return v;
}

// row window: only lw (x-1) and rx (x+4) cross the chunk -> b128 + 2x b32
struct RowS { float lw; float4 m; float rx; };
__device__ __forceinline__ RowS load_rowS(const float* A, int base, int lo, int ro){
  RowS q; q.m = lds4(A, base); q.lw = A[base+lo]; q.rx = A[base+ro]; return q;
}
__device__ __forceinline__ float4 dxvS(const RowS& q){
  return make_float4(q.m.y - q.lw, q.m.z - q.m.x, q.m.w - q.m.y, q.rx - q.m.z);
}
__device__ __forceinline__ void sobel_rowsS(const RowS& A, const RowS& B, const RowS& C,
                                            float4& rgx, float4& rgy){
  float4 da = dxvS(A), db = dxvS(B), dc = dxvS(C);
  rgx.x = (da.x + 2.f*db.x + dc.x) * 0.125f;
  rgx.y = (da.y + 2.f*db.y + dc.y) * 0.125f;
  rgx.z = (da.z + 2.f*db.z + dc.z) * 0.125f;
  rgx.w = (da.w + 2.f*db.w + dc.w) * 0.125f;
  float cm1 = C.lw - A.lw;
  float c0 = C.m.x - A.m.x, c1 = C.m.y - A.m.y;
  float c2 = C.m.z - A.m.z, c3 = C.m.w - A.m.w;
  float c4 = C.rx - A.rx;
  rgy.x = (cm1 + 2.f*c0 + c1) * 0.125f;
  rgy.y = (c0  + 2.f*c1 + c2) * 0.125f;
  rgy.z = (c1  + 2.f*c2 + c3) * 0.125f;
  rgy.w = (c2  + 2.f*c3 + c4) * 0.125f;
}
__device__ __forceinline__ void p_elem(float4 rgx, float4 rgy, float4 pa, float4 pb,
                                       float4 gg, float4& n1, float4& n2){
#define PE(c) { \
    float mag = __builtin_amdgcn_sqrtf(rgx.c*rgx.c + rgy.c*rgy.c); \
    float inv = __builtin_amdgcn_rcpf(1.f + 0.125f*mag*gg.c); \
    n1.c = (pa.c + 0.125f*rgx.c)*inv; n2.c = (pb.c + 0.125f*rgy.c)*inv; }
  PE(x) PE(y) PE(z) PE(w)
#undef PE
}

// paired-row p-update, in place on P1s/P2s, sobel of Rs
template<bool EDGE>
__device__ __forceinline__ void p_phase(const float* Rs, float* P1s, float* P2s,
    const float* gb, int x0, int y0, int tid, int ylo, int npairs){
  int total = npairs * 20;
  for (int i = tid; i < total; i += NTH){
    int pr = i / 20, cx = i - pr*20;
    int x = cx*4 - 8;
    int y = ylo + pr*2;
    int col = x + 8;                      // column in V/R coords (stride 80)
    int lo = (col==0) ? 0 : -1;           // clamped reads feed junk cells only
    int ro = (col==76) ? 0 : 4;
    int base = VIDX(y,x);
    RowS Rm1 = load_rowS(Rs, base-VW2,   lo, ro);
    RowS R0  = load_rowS(Rs, base,       lo, ro);
    RowS R1  = load_rowS(Rs, base+VW2,   lo, ro);
    RowS R2  = load_rowS(Rs, base+2*VW2, lo, ro);
    float4 rgx0, rgy0, rgx1, rgy1;
    sobel_rowsS(Rm1, R0, R1, rgx0, rgy0);
    sobel_rowsS(R0,  R1, R2, rgx1, rgy1);
    int p0 = PIDX(y,x), p1i = p0 + PW2;
    float4 pa0 = lds4(P1s,p0),  pb0 = lds4(P2s,p0);
    float4 pa1 = lds4(P1s,p1i), pb1 = lds4(P2s,p1i);
    float4 g0 = gld4<EDGE>(gb, y0+y,   x0+x);
    float4 g1 = gld4<EDGE>(gb, y0+y+1, x0+x);
    float4 n10,n20,n11,n21;
    p_elem(rgx0,rgy0,pa0,pb0,g0,n10,n20);
    p_elem(rgx1,rgy1,pa1,pb1,g1,n11,n21);
    if (EDGE){
      n10 = mask4(n10, y0+y,   x0+x); n20 = mask4(n20, y0+y,   x0+x);
      n11 = mask4(n11, y0+y+1, x0+x); n21 = mask4(n21, y0+y+1, x0+x);
    }
    sts4(P1s,p0,n10);  sts4(P2s,p0,n20);
    sts4(P1s,p1i,n11); sts4(P2s,p1i,n21);
  }
}

// v-update (in place on Vs, skipped when FIRSTR) + r = div(p) - f + v -> Rs
template<bool EDGE, bool FIRSTR>
__device__ __forceinline__ void vr_phase(float* Rs, const float* P1s, const float* P2s,
    float* Vs, const float* fb, int x0, int y0, int tid, int ylo, int nrows){
  int total = nrows * 20;
  for (int i = tid; i < total; i += NTH){
    int cy = i / 20, cx = i - cy*20;
    int x = cx*4 - 8, y = ylo + cy;
    int pc = PIDX(y,x);
    float4 m = lds4(P1s,pc);
    float lw = P1s[pc-1], rx = P1s[pc+4];
    float4 up = lds4(P2s,pc-PW2), dn = lds4(P2s,pc+PW2);
    float4 db;
    db.x = (m.y - lw)  + (dn.x - up.x);
    db.y = (m.z - m.x) + (dn.y - up.y);
    db.z = (m.w - m.y) + (dn.z - up.z);
    db.w = (rx  - m.z) + (dn.w - up.w);
    int vi = VIDX(y,x);
    float4 vv = lds4(Vs, vi);
    float4 ff = gld4<EDGE>(fb, y0+y, x0+x);
    float4 rv;
    if (FIRSTR){
      rv.x = db.x - ff.x + vv.x; rv.y = db.y - ff.y + vv.y;
      rv.z = db.z - ff.z + vv.z; rv.w = db.w - ff.w + vv.w;
      if (EDGE) rv = mask4(rv, y0+y, x0+x);
      sts4(Rs, vi, rv);
    } else {
      float4 vn;
      vn.x = shrink01(vv.x + db.x); vn.y = shrink01(vv.y + db.y);
      vn.z = shrink01(vv.z + db.z); vn.w = shrink01(vv.w + db.w);
      rv.x = db.x - ff.x + vn.x; rv.y = db.y - ff.y + vn.y;
      rv.z = db.z - ff.z + vn.z; rv.w = db.w - ff.w + vn.w;
      if (EDGE){ vn = mask4(vn, y0+y, x0+x); rv = mask4(rv, y0+y, x0+x); }
      sts4(Vs, vi, vn);
      sts4(Rs, vi, rv);
    }
  }
}

template<bool FIRST, bool LAST, bool EDGE>
__device__ __forceinline__ void iter_body4(
    const float* fb, const float* gb,
    const float* p1b, const float* p2b, const float* vb,
    float* p1o, float* p2o, float* vo, float* uo,
    int x0, int y0, int tid,
    float* P1s, float* P2s, float* Vs, float* Rs)
{
  // ---- stage p (halo 9, padded to 12) and v (halo 8)
  for (int i = tid; i < 50*22; i += NTH){
    int cy = i / 22, cx = i - cy*22;
    int x = cx*4 - 12, y = cy - 9;
    float4 a, b;
    if (FIRST){ a = f4zero(); b = f4zero(); }
    else {
      int gy = y0+y, gx = x0+x;
      a = gld4<EDGE>(p1b, gy, gx); b = gld4<EDGE>(p2b, gy, gx);
      if (EDGE){ a = mask4(a,gy,gx); b = mask4(b,gy,gx); }
    }
    int idx = PIDX(y,x);
    sts4(P1s, idx, a); sts4(P2s, idx, b);
  }
  for (int i = tid; i < 48*20; i += NTH){
    int cy = i / 20, cx = i - cy*20;
    int x = cx*4 - 8, y = cy - 8;
    float4 v;
    if (FIRST) v = f4zero();
    else {
      int gy = y0+y, gx = x0+x;
      v = gld4<EDGE>(vb, gy, gx);
      if (EDGE) v = mask4(v, gy, gx);
    }
    sts4(Vs, VIDX(y,x), v);
  }
  __syncthreads();

  // ---- 4 fused iterations, halo ladder 8->1
  vr_phase<EDGE,true >(Rs,P1s,P2s,Vs,fb,x0,y0,tid,-8,48); __syncthreads();
  p_phase<EDGE>(Rs,P1s,P2s,gb,x0,y0,tid,-7,23);           __syncthreads();
  vr_phase<EDGE,false>(Rs,P1s,P2s,Vs,fb,x0,y0,tid,-6,44); __syncthreads();
  p_phase<EDGE>(Rs,P1s,P2s,gb,x0,y0,tid,-5,21);           __syncthreads();
  vr_phase<EDGE,false>(Rs,P1s,P2s,Vs,fb,x0,y0,tid,-4,40); __syncthreads();
  p_phase<EDGE>(Rs,P1s,P2s,gb,x0,y0,tid,-3,19);           __syncthreads();
  vr_phase<EDGE,false>(Rs,P1s,P2s,Vs,fb,x0,y0,tid,-2,36); __syncthreads();
  p_phase<EDGE>(Rs,P1s,P2s,gb,x0,y0,tid,-1,17);           __syncthreads();

  // ---- outputs over owned tile (512 chunks, one per thread)
  {
    int i = tid;
    int cy = i >> 4, cx = i & 15;
    int x = cx*4, y = cy;
    int pc = PIDX(y,x);
    float4 m = lds4(P1s,pc);
    float lw = P1s[pc-1], rx = P1s[pc+4];
    float4 up = lds4(P2s,pc-PW2), dn = lds4(P2s,pc+PW2);
    float4 dq;
    dq.x = (m.y - lw)  + (dn.x - up.x);
    dq.y = (m.z - m.x) + (dn.y - up.y);
    dq.z = (m.w - m.y) + (dn.z - up.z);
    dq.w = (rx  - m.z) + (dn.w - up.w);
    float4 vv = lds4(Vs, VIDX(y,x));   // v3 (pre-update v of iter 4)
    size_t go = (size_t)(y0+y)*IMW + (x0+x);
    if (LAST){
      float4 ff = gld4<false>(fb, y0+y, x0+x);
      float4 uu;
      uu.x = ff.x - vv.x - dq.x; uu.y = ff.y - vv.y - dq.y;
      uu.z = ff.z - vv.z - dq.z; uu.w = ff.w - vv.w - dq.w;
      *(float4*)(uo + go) = uu;
    } else {
      float4 m2 = lds4(P2s,pc);
      float4 vn;
      vn.x = shrink01(vv.x + dq.x); vn.y = shrink01(vv.y + dq.y);
      vn.z = shrink01(vv.z + dq.z); vn.w = shrink01(vv.w + dq.w);
      *(float4*)(p1o + go) = m;
      *(float4*)(p2o + go) = m2;
      *(float4*)(vo  + go) = vn;
    }
  }
}

template<bool FIRST, bool LAST>
__global__ __launch_bounds__(NTH, 4) void iter4_kernel(
    const float* __restrict__ f, const float* __restrict__ ginv,
    const float* __restrict__ p1in, const float* __restrict__ p2in,
    const float* __restrict__ vin,
    float* __restrict__ p1out, float* __restrict__ p2out,
    float* __restrict__ vout, float* __restrict__ uout)
{
  __shared__ alignas(16) float P1s[P_H2*PW2], P2s[P_H2*PW2];
  __shared__ alignas(16) float Vs[V_H2*VW2], Rs[V_H2*VW2];

  int phys = blockIdx.x;
  int virt = (phys & 7) * (NBLK/8) + (phys >> 3);   // XCD-chunked, bijective
  int bx = virt & (GXT-1);
  int by = (virt >> 3) & (GYT-1);
  int b  = virt >> 7;
  int x0 = bx*TX, y0 = by*TY;
  size_t boff = (size_t)b * NPIX;
  bool edge = (bx==0) | (bx==GXT-1) | (by==0) | (by==GYT-1);
  int tid = threadIdx.x;

  if (edge)
    iter_body4<FIRST,LAST,true>(f+boff, ginv+boff, p1in+boff, p2in+boff, vin+boff,
        p1out+boff, p2out+boff, vout+boff, uout+boff, x0, y0, tid,
        P1s, P2s, Vs, Rs);
  else
    iter_body4<FIRST,LAST,false>(f+boff, ginv+boff, p1in+boff, p2in+boff, vin+boff,
        p1out+boff, p2out+boff, vout+boff, uout+boff, x0, y0, tid,
        P1s, P2s, Vs, Rs);
}

// ginv = 1 + gx^2 + gy^2, vectorized: one f4 chunk per thread
__global__ __launch_bounds__(256) void init_kernel(
    const float* __restrict__ f, float* __restrict__ ginv) {
  int i = blockIdx.x * 256 + threadIdx.x;       // 262144 chunks total
  int b = i >> 16; int rem = i & 0xFFFF;
  int gy = rem >> 7; int gx = (rem & 127) * 4;
  const float* fb = f + (size_t)b * NPIX;
  float L[3], R[3]; float4 O[3];
  for (int k = 0; k < 3; ++k){
    int y = gy + k - 1;
    if ((unsigned)y < (unsigned)IMH){
      const float* rp = fb + (size_t)y*IMW + gx;
      O[k] = *(const float4*)rp;
      L[k] = (gx > 0) ? rp[-1] : 0.f;
      R[k] = (gx < IMW-4) ? rp[4] : 0.f;
    } else { O[k] = f4zero(); L[k] = 0.f; R[k] = 0.f; }
  }
  float4 out;
#define GE(c, im1, i0, ip1) { \
    float sx = (i0##_p - i0##_m)*2.f + (im1##_p - im1##_m) + (ip1##_p - ip1##_m); \
    float sy = (ip1##_m - im1##_m) + 2.f*(ip1##_c - im1##_c) + (ip1##_p - im1##_p); \
    out.c = 1.f + sx*sx + sy*sy; }
  { float a_m=L[0], a_c=O[0].x, a_p=O[0].y;
    float b_m=L[1], b_c=O[1].x, b_p=O[1].y;
    float c_m=L[2], c_c=O[2].x, c_p=O[2].y;
    GE(x, a, b, c) }
  { float a_m=O[0].x, a_c=O[0].y, a_p=O[0].z;
    float b_m=O[1].x, b_c=O[1].y, b_p=O[1].z;
    float c_m=O[2].x, c_c=O[2].y, c_p=O[2].z;
    GE(y, a, b, c) }
  { float a_m=O[0].y, a_c=O[0].z, a_p=O[0].w;
    float b_m=O[1].y, b_c=O[1].z, b_p=O[1].w;
    float c_m=O[2].y, c_c=O[2].z, c_p=O[2].w;
    GE(z, a, b, c) }
  { float a_m=O[0].z, a_c=O[0].w, a_p=R[0];
    float b_m=O[1].z, b_c=O[1].w, b_p=R[1];
    float c_m=O[2].z, c_c=O[2].w, c_p=R[2];
    GE(w, a, b, c) }
#undef GE
  *(float4*)(ginv + (size_t)b*NPIX + (size_t)gy*IMW + gx) = out;
}

extern "C" void kernel_launch(void* const* d_in, const int* in_sizes, int n_in,
                              void* d_out, int out_size, void* d_ws, size_t ws_size,
                              hipStream_t stream) {
  const float* f = (const float*)d_in[0];
  float* u = (float*)d_out;
  float* ws = (float*)d_ws;
  const size_t N = (size_t)NB * NPIX;
  float* g   = ws + 0*N;
  float* p1a = ws + 1*N;
  float* p2a = ws + 2*N;
  float* va  = ws + 3*N;
  float* p1b = ws + 4*N;
  float* p2b = ws + 5*N;
  float* vb  = ws + 6*N;

  init_kernel<<<1024, 256, 0, stream>>>(f, g);

  for (int l = 0; l < 25; ++l) {   // 25 x 4 fused = 100 iterations
    const float *pi1, *pi2, *vi;
    float *po1, *po2, *vo;
    if (l & 1) { pi1 = p1b; pi2 = p2b; vi = vb; po1 = p1a; po2 = p2a; vo = va; }
    else       { pi1 = p1a; pi2 = p2a; vi = va; po1 = p1b; po2 = p2b; vo = vb; }
    if (l == 0)
      iter4_kernel<true, false><<<NBLK, NTH, 0, stream>>>(f, g, pi1, pi2, vi, po1, po2, vo, u);
    else if (l == 24)
      iter4_kernel<false, true><<<NBLK, NTH, 0, stream>>>(f, g, pi1, pi2, vi, po1, po2, vo, u);
    else
      iter4_kernel<false, false><<<NBLK, NTH, 0, stream>>>(f, g, pi1, pi2, vi, po1, po2, vo, u);
  }
}

// Round 7
// 409.983 us; speedup vs baseline: 24.3933x; 1.1179x over previous
//
#include <hip/hip_runtime.h>

#define IMH 512
#define IMW 512
#define NB 4
#define NPIX (IMH*IMW)

#define TX 64
#define TY 32
#define GXT 8                 // IMW/TX
#define GYT 16                // IMH/TY
#define NBLK (GXT*GYT*NB)     // 512  == 2 blocks/CU exactly
#define NTH 1024              // 16 waves/block -> 32 waves/CU (max occupancy)

// k=4 fusion, in-place LDS state (ladder: p0@9,v0@8 -> r1@8 -> p1@7 -> {v1,r2}@6
//  -> p2@5 -> {v2,r3}@4 -> p3@3 -> {v3,r4}@2 -> p4@1 -> out@0):
// P (p): y in [-9,41) = 50 rows, x in [-12,76) stride 88   (holds p0->p1->p2->p3->p4)
// V (v): y in [-8,40) = 48 rows, x in [-8,72)  stride 80   (holds v0->v1->v2->v3)
// R (r): same dims as V                                     (holds r1->r2->r3->r4)
// Total LDS = (50*88*2 + 48*80*2)*4 = 65,920 B -> 2 blocks/CU on 160 KiB.
#define PW2 88
#define P_H2 50
#define VW2 80
#define V_H2 48

#define PIDX(y,x) (((y)+9)*PW2 + ((x)+12))
#define VIDX(y,x) (((y)+8)*VW2 + ((x)+8))

__device__ __forceinline__ float4 lds4(const float* p, int i){ return *(const float4*)(p + i); }
__device__ __forceinline__ void  sts4(float* p, int i, float4 v){ *(float4*)(p + i) = v; }
__device__ __forceinline__ float4 f4zero(){ return make_float4(0.f,0.f,0.f,0.f); }
__device__ __forceinline__ float shrink01(float d){
  return d - fminf(fmaxf(d, -0.1f), 0.1f);   // v_med3 idiom
}

template<bool EDGE>
__device__ __forceinline__ float4 gld4(const float* base, int gy, int gx){
  if (EDGE){ gy = min(max(gy,0),IMH-1); gx = min(max(gx,0),IMW-4); }
  return *(const float4*)(base + gy*IMW + gx);
}
__device__ __forceinline__ float4 mask4(float4 v, int gy, int gx){
  if ((unsigned)gy >= (unsigned)IMH) return f4zero();
  v.x = ((unsigned)(gx+0) < (unsigned)IMW) ? v.x : 0.f;
  v.y = ((unsigned)(gx+1) < (unsigned)IMW) ? v.y : 0.f;
  v.z = ((unsigned)(gx+2) < (unsigned)IMW) ? v.z : 0.f;
  v.w = ((unsigned)(gx+3) < (unsigned)IMW) ? v.w : 0.f;
  return v;
}

// row window: only lw (x-1) and rx (x+4) cross the chunk -> b128 + 2x b32
struct RowS { float lw; float4 m; float rx; };
__device__ __forceinline__ RowS load_rowS(const float* A, int base, int lo, int ro){
  RowS q; q.m = lds4(A, base); q.lw = A[base+lo]; q.rx = A[base+ro]; return q;
}
__device__ __forceinline__ float4 dxvS(const RowS& q){
  return make_float4(q.m.y - q.lw, q.m.z - q.m.x, q.m.w - q.m.y, q.rx - q.m.z);
}
__device__ __forceinline__ void sobel_rowsS(const RowS& A, const RowS& B, const RowS& C,
                                            float4& rgx, float4& rgy){
  float4 da = dxvS(A), db = dxvS(B), dc = dxvS(C);
  rgx.x = (da.x + 2.f*db.x + dc.x) * 0.125f;
  rgx.y = (da.y + 2.f*db.y + dc.y) * 0.125f;
  rgx.z = (da.z + 2.f*db.z + dc.z) * 0.125f;
  rgx.w = (da.w + 2.f*db.w + dc.w) * 0.125f;
  float cm1 = C.lw - A.lw;
  float c0 = C.m.x - A.m.x, c1 = C.m.y - A.m.y;
  float c2 = C.m.z - A.m.z, c3 = C.m.w - A.m.w;
  float c4 = C.rx - A.rx;
  rgy.x = (cm1 + 2.f*c0 + c1) * 0.125f;
  rgy.y = (c0  + 2.f*c1 + c2) * 0.125f;
  rgy.z = (c1  + 2.f*c2 + c3) * 0.125f;
  rgy.w = (c2  + 2.f*c3 + c4) * 0.125f;
}
__device__ __forceinline__ void p_elem(float4 rgx, float4 rgy, float4 pa, float4 pb,
                                       float4 gg, float4& n1, float4& n2){
#define PE(c) { \
    float mag = __builtin_amdgcn_sqrtf(rgx.c*rgx.c + rgy.c*rgy.c); \
    float inv = __builtin_amdgcn_rcpf(1.f + 0.125f*mag*gg.c); \
    n1.c = (pa.c + 0.125f*rgx.c)*inv; n2.c = (pb.c + 0.125f*rgy.c)*inv; }
  PE(x) PE(y) PE(z) PE(w)
#undef PE
}

// single-row p-update, in place on P1s/P2s, sobel of Rs (low VGPR for 1024thr)
template<bool EDGE>
__device__ __forceinline__ void p_phase(const float* Rs, float* P1s, float* P2s,
    const float* gb, int x0, int y0, int tid, int ylo, int nrows){
  int total = nrows * 20;
  for (int i = tid; i < total; i += NTH){
    int cy = i / 20, cx = i - cy*20;
    int x = cx*4 - 8;
    int y = ylo + cy;
    int col = x + 8;                      // column in V/R coords (stride 80)
    int lo = (col==0) ? 0 : -1;           // clamped reads feed junk cells only
    int ro = (col==76) ? 0 : 4;
    int base = VIDX(y,x);
    RowS Rm1 = load_rowS(Rs, base-VW2, lo, ro);
    RowS R0  = load_rowS(Rs, base,     lo, ro);
    RowS R1  = load_rowS(Rs, base+VW2, lo, ro);
    float4 rgx, rgy;
    sobel_rowsS(Rm1, R0, R1, rgx, rgy);
    int p0 = PIDX(y,x);
    float4 pa = lds4(P1s,p0), pb = lds4(P2s,p0);
    float4 g0 = gld4<EDGE>(gb, y0+y, x0+x);
    float4 n1, n2;
    p_elem(rgx,rgy,pa,pb,g0,n1,n2);
    if (EDGE){
      n1 = mask4(n1, y0+y, x0+x); n2 = mask4(n2, y0+y, x0+x);
    }
    sts4(P1s,p0,n1); sts4(P2s,p0,n2);
  }
}

// v-update (in place on Vs, skipped when FIRSTR) + r = div(p) - f + v -> Rs
template<bool EDGE, bool FIRSTR>
__device__ __forceinline__ void vr_phase(float* Rs, const float* P1s, const float* P2s,
    float* Vs, const float* fb, int x0, int y0, int tid, int ylo, int nrows){
  int total = nrows * 20;
  for (int i = tid; i < total; i += NTH){
    int cy = i / 20, cx = i - cy*20;
    int x = cx*4 - 8, y = ylo + cy;
    int pc = PIDX(y,x);
    float4 m = lds4(P1s,pc);
    float lw = P1s[pc-1], rx = P1s[pc+4];
    float4 up = lds4(P2s,pc-PW2), dn = lds4(P2s,pc+PW2);
    float4 db;
    db.x = (m.y - lw)  + (dn.x - up.x);
    db.y = (m.z - m.x) + (dn.y - up.y);
    db.z = (m.w - m.y) + (dn.z - up.z);
    db.w = (rx  - m.z) + (dn.w - up.w);
    int vi = VIDX(y,x);
    float4 vv = lds4(Vs, vi);
    float4 ff = gld4<EDGE>(fb, y0+y, x0+x);
    float4 rv;
    if (FIRSTR){
      rv.x = db.x - ff.x + vv.x; rv.y = db.y - ff.y + vv.y;
      rv.z = db.z - ff.z + vv.z; rv.w = db.w - ff.w + vv.w;
      if (EDGE) rv = mask4(rv, y0+y, x0+x);
      sts4(Rs, vi, rv);
    } else {
      float4 vn;
      vn.x = shrink01(vv.x + db.x); vn.y = shrink01(vv.y + db.y);
      vn.z = shrink01(vv.z + db.z); vn.w = shrink01(vv.w + db.w);
      rv.x = db.x - ff.x + vn.x; rv.y = db.y - ff.y + vn.y;
      rv.z = db.z - ff.z + vn.z; rv.w = db.w - ff.w + vn.w;
      if (EDGE){ vn = mask4(vn, y0+y, x0+x); rv = mask4(rv, y0+y, x0+x); }
      sts4(Vs, vi, vn);
      sts4(Rs, vi, rv);
    }
  }
}

template<bool FIRST, bool LAST, bool EDGE>
__device__ __forceinline__ void iter_body4(
    const float* fb, const float* gb,
    const float* p1b, const float* p2b, const float* vb,
    float* p1o, float* p2o, float* vo, float* uo,
    int x0, int y0, int tid,
    float* P1s, float* P2s, float* Vs, float* Rs)
{
  // ---- stage p (halo 9, padded to 12) and v (halo 8)
  for (int i = tid; i < 50*22; i += NTH){
    int cy = i / 22, cx = i - cy*22;
    int x = cx*4 - 12, y = cy - 9;
    float4 a, b;
    if (FIRST){ a = f4zero(); b = f4zero(); }
    else {
      int gy = y0+y, gx = x0+x;
      a = gld4<EDGE>(p1b, gy, gx); b = gld4<EDGE>(p2b, gy, gx);
      if (EDGE){ a = mask4(a,gy,gx); b = mask4(b,gy,gx); }
    }
    int idx = PIDX(y,x);
    sts4(P1s, idx, a); sts4(P2s, idx, b);
  }
  for (int i = tid; i < 48*20; i += NTH){
    int cy = i / 20, cx = i - cy*20;
    int x = cx*4 - 8, y = cy - 8;
    float4 v;
    if (FIRST) v = f4zero();
    else {
      int gy = y0+y, gx = x0+x;
      v = gld4<EDGE>(vb, gy, gx);
      if (EDGE) v = mask4(v, gy, gx);
    }
    sts4(Vs, VIDX(y,x), v);
  }
  __syncthreads();

  // ---- 4 fused iterations, halo ladder 8->1
  vr_phase<EDGE,true >(Rs,P1s,P2s,Vs,fb,x0,y0,tid,-8,48); __syncthreads();
  p_phase<EDGE>(Rs,P1s,P2s,gb,x0,y0,tid,-7,46);           __syncthreads();
  vr_phase<EDGE,false>(Rs,P1s,P2s,Vs,fb,x0,y0,tid,-6,44); __syncthreads();
  p_phase<EDGE>(Rs,P1s,P2s,gb,x0,y0,tid,-5,42);           __syncthreads();
  vr_phase<EDGE,false>(Rs,P1s,P2s,Vs,fb,x0,y0,tid,-4,40); __syncthreads();
  p_phase<EDGE>(Rs,P1s,P2s,gb,x0,y0,tid,-3,38);           __syncthreads();
  vr_phase<EDGE,false>(Rs,P1s,P2s,Vs,fb,x0,y0,tid,-2,36); __syncthreads();
  p_phase<EDGE>(Rs,P1s,P2s,gb,x0,y0,tid,-1,34);           __syncthreads();

  // ---- outputs over owned tile (512 chunks)
  if (tid < 512){
    int i = tid;
    int cy = i >> 4, cx = i & 15;
    int x = cx*4, y = cy;
    int pc = PIDX(y,x);
    float4 m = lds4(P1s,pc);
    float lw = P1s[pc-1], rx = P1s[pc+4];
    float4 up = lds4(P2s,pc-PW2), dn = lds4(P2s,pc+PW2);
    float4 dq;
    dq.x = (m.y - lw)  + (dn.x - up.x);
    dq.y = (m.z - m.x) + (dn.y - up.y);
    dq.z = (m.w - m.y) + (dn.z - up.z);
    dq.w = (rx  - m.z) + (dn.w - up.w);
    float4 vv = lds4(Vs, VIDX(y,x));   // v3 (pre-update v of iter 4)
    size_t go = (size_t)(y0+y)*IMW + (x0+x);
    if (LAST){
      float4 ff = gld4<false>(fb, y0+y, x0+x);
      float4 uu;
      uu.x = ff.x - vv.x - dq.x; uu.y = ff.y - vv.y - dq.y;
      uu.z = ff.z - vv.z - dq.z; uu.w = ff.w - vv.w - dq.w;
      *(float4*)(uo + go) = uu;
    } else {
      float4 m2 = lds4(P2s,pc);
      float4 vn;
      vn.x = shrink01(vv.x + dq.x); vn.y = shrink01(vv.y + dq.y);
      vn.z = shrink01(vv.z + dq.z); vn.w = shrink01(vv.w + dq.w);
      *(float4*)(p1o + go) = m;
      *(float4*)(p2o + go) = m2;
      *(float4*)(vo  + go) = vn;
    }
  }
}

template<bool FIRST, bool LAST>
__global__ __launch_bounds__(NTH, 8) void iter4_kernel(
    const float* __restrict__ f, const float* __restrict__ ginv,
    const float* __restrict__ p1in, const float* __restrict__ p2in,
    const float* __restrict__ vin,
    float* __restrict__ p1out, float* __restrict__ p2out,
    float* __restrict__ vout, float* __restrict__ uout)
{
  __shared__ alignas(16) float P1s[P_H2*PW2], P2s[P_H2*PW2];
  __shared__ alignas(16) float Vs[V_H2*VW2], Rs[V_H2*VW2];

  int phys = blockIdx.x;
  int virt = (phys & 7) * (NBLK/8) + (phys >> 3);   // XCD-chunked, bijective
  int bx = virt & (GXT-1);
  int by = (virt >> 3) & (GYT-1);
  int b  = virt >> 7;
  int x0 = bx*TX, y0 = by*TY;
  size_t boff = (size_t)b * NPIX;
  bool edge = (bx==0) | (bx==GXT-1) | (by==0) | (by==GYT-1);
  int tid = threadIdx.x;

  if (edge)
    iter_body4<FIRST,LAST,true>(f+boff, ginv+boff, p1in+boff, p2in+boff, vin+boff,
        p1out+boff, p2out+boff, vout+boff, uout+boff, x0, y0, tid,
        P1s, P2s, Vs, Rs);
  else
    iter_body4<FIRST,LAST,false>(f+boff, ginv+boff, p1in+boff, p2in+boff, vin+boff,
        p1out+boff, p2out+boff, vout+boff, uout+boff, x0, y0, tid,
        P1s, P2s, Vs, Rs);
}

// ginv = 1 + gx^2 + gy^2, vectorized: one f4 chunk per thread
__global__ __launch_bounds__(256) void init_kernel(
    const float* __restrict__ f, float* __restrict__ ginv) {
  int i = blockIdx.x * 256 + threadIdx.x;       // 262144 chunks total
  int b = i >> 16; int rem = i & 0xFFFF;
  int gy = rem >> 7; int gx = (rem & 127) * 4;
  const float* fb = f + (size_t)b * NPIX;
  float L[3], R[3]; float4 O[3];
  for (int k = 0; k < 3; ++k){
    int y = gy + k - 1;
    if ((unsigned)y < (unsigned)IMH){
      const float* rp = fb + (size_t)y*IMW + gx;
      O[k] = *(const float4*)rp;
      L[k] = (gx > 0) ? rp[-1] : 0.f;
      R[k] = (gx < IMW-4) ? rp[4] : 0.f;
    } else { O[k] = f4zero(); L[k] = 0.f; R[k] = 0.f; }
  }
  float4 out;
#define GE(c, im1, i0, ip1) { \
    float sx = (i0##_p - i0##_m)*2.f + (im1##_p - im1##_m) + (ip1##_p - ip1##_m); \
    float sy = (ip1##_m - im1##_m) + 2.f*(ip1##_c - im1##_c) + (ip1##_p - im1##_p); \
    out.c = 1.f + sx*sx + sy*sy; }
  { float a_m=L[0], a_c=O[0].x, a_p=O[0].y;
    float b_m=L[1], b_c=O[1].x, b_p=O[1].y;
    float c_m=L[2], c_c=O[2].x, c_p=O[2].y;
    GE(x, a, b, c) }
  { float a_m=O[0].x, a_c=O[0].y, a_p=O[0].z;
    float b_m=O[1].x, b_c=O[1].y, b_p=O[1].z;
    float c_m=O[2].x, c_c=O[2].y, c_p=O[2].z;
    GE(y, a, b, c) }
  { float a_m=O[0].y, a_c=O[0].z, a_p=O[0].w;
    float b_m=O[1].y, b_c=O[1].z, b_p=O[1].w;
    float c_m=O[2].y, c_c=O[2].z, c_p=O[2].w;
    GE(z, a, b, c) }
  { float a_m=O[0].z, a_c=O[0].w, a_p=R[0];
    float b_m=O[1].z, b_c=O[1].w, b_p=R[1];
    float c_m=O[2].z, c_c=O[2].w, c_p=R[2];
    GE(w, a, b, c) }
#undef GE
  *(float4*)(ginv + (size_t)b*NPIX + (size_t)gy*IMW + gx) = out;
}

extern "C" void kernel_launch(void* const* d_in, const int* in_sizes, int n_in,
                              void* d_out, int out_size, void* d_ws, size_t ws_size,
                              hipStream_t stream) {
  const float* f = (const float*)d_in[0];
  float* u = (float*)d_out;
  float* ws = (float*)d_ws;
  const size_t N = (size_t)NB * NPIX;
  float* g   = ws + 0*N;
  float* p1a = ws + 1*N;
  float* p2a = ws + 2*N;
  float* va  = ws + 3*N;
  float* p1b = ws + 4*N;
  float* p2b = ws + 5*N;
  float* vb  = ws + 6*N;

  init_kernel<<<1024, 256, 0, stream>>>(f, g);

  for (int l = 0; l < 25; ++l) {   // 25 x 4 fused = 100 iterations
    const float *pi1, *pi2, *vi;
    float *po1, *po2, *vo;
    if (l & 1) { pi1 = p1b; pi2 = p2b; vi = vb; po1 = p1a; po2 = p2a; vo = va; }
    else       { pi1 = p1a; pi2 = p2a; vi = va; po1 = p1b; po2 = p2b; vo = vb; }
    if (l == 0)
      iter4_kernel<true, false><<<NBLK, NTH, 0, stream>>>(f, g, pi1, pi2, vi, po1, po2, vo, u);
    else if (l == 24)
      iter4_kernel<false, true><<<NBLK, NTH, 0, stream>>>(f, g, pi1, pi2, vi, po1, po2, vo, u);
    else
      iter4_kernel<false, false><<<NBLK, NTH, 0, stream>>>(f, g, pi1, pi2, vi, po1, po2, vo, u);
  }
}

// Round 8
// 394.926 us; speedup vs baseline: 25.3233x; 1.0381x over previous
//
#include <hip/hip_runtime.h>

#define IMH 512
#define IMW 512
#define NB 4
#define NPIX (IMH*IMW)

#define TX 64
#define TY 32
#define GXT 8                 // IMW/TX
#define GYT 16                // IMH/TY
#define NBLK (GXT*GYT*NB)     // 512  == 2 blocks/CU exactly
#define NTH 1024              // 16 waves/block -> 32 waves/CU (max occupancy)

// k=4 fusion, in-place LDS state; v lives in REGISTERS (cell-local state):
// P (p): y in [-9,41) = 50 rows, x in [-12,76) stride 88   (p0->p1->p2->p3->p4)
// R (r): y in [-8,40) = 48 rows, x in [-8,72)  stride 80   (r1->r2->r3->r4)
// v: one float4 chunk per thread, fixed ownership (48x20 chunks = 960 threads)
// Total LDS = (50*88*2 + 48*80)*4 = 50,560 B -> 2 blocks/CU (wave-count capped).
#define PW2 88
#define P_H2 50
#define VW2 80
#define V_H2 48

#define PIDX(y,x) (((y)+9)*PW2 + ((x)+12))
#define VIDX(y,x) (((y)+8)*VW2 + ((x)+8))

__device__ __forceinline__ float4 lds4(const float* p, int i){ return *(const float4*)(p + i); }
__device__ __forceinline__ void  sts4(float* p, int i, float4 v){ *(float4*)(p + i) = v; }
__device__ __forceinline__ float4 f4zero(){ return make_float4(0.f,0.f,0.f,0.f); }
__device__ __forceinline__ float shrink01(float d){
  return d - fminf(fmaxf(d, -0.1f), 0.1f);   // v_med3 idiom
}

template<bool EDGE>
__device__ __forceinline__ float4 gld4(const float* base, int gy, int gx){
  if (EDGE){ gy = min(max(gy,0),IMH-1); gx = min(max(gx,0),IMW-4); }
  return *(const float4*)(base + gy*IMW + gx);
}
__device__ __forceinline__ float4 mask4(float4 v, int gy, int gx){
  if ((unsigned)gy >= (unsigned)IMH) return f4zero();
  v.x = ((unsigned)(gx+0) < (unsigned)IMW) ? v.x : 0.f;
  v.y = ((unsigned)(gx+1) < (unsigned)IMW) ? v.y : 0.f;
  v.z = ((unsigned)(gx+2) < (unsigned)IMW) ? v.z : 0.f;
  v.w = ((unsigned)(gx+3) < (unsigned)IMW) ? v.w : 0.f;
  return v;
}

// row window: only lw (x-1) and rx (x+4) cross the chunk -> b128 + 2x b32
struct RowS { float lw; float4 m; float rx; };
__device__ __forceinline__ RowS load_rowS(const float* A, int base, int lo, int ro){
  RowS q; q.m = lds4(A, base); q.lw = A[base+lo]; q.rx = A[base+ro]; return q;
}
__device__ __forceinline__ float4 dxvS(const RowS& q){
  return make_float4(q.m.y - q.lw, q.m.z - q.m.x, q.m.w - q.m.y, q.rx - q.m.z);
}
__device__ __forceinline__ void sobel_rowsS(const RowS& A, const RowS& B, const RowS& C,
                                            float4& rgx, float4& rgy){
  float4 da = dxvS(A), db = dxvS(B), dc = dxvS(C);
  rgx.x = (da.x + 2.f*db.x + dc.x) * 0.125f;
  rgx.y = (da.y + 2.f*db.y + dc.y) * 0.125f;
  rgx.z = (da.z + 2.f*db.z + dc.z) * 0.125f;
  rgx.w = (da.w + 2.f*db.w + dc.w) * 0.125f;
  float cm1 = C.lw - A.lw;
  float c0 = C.m.x - A.m.x, c1 = C.m.y - A.m.y;
  float c2 = C.m.z - A.m.z, c3 = C.m.w - A.m.w;
  float c4 = C.rx - A.rx;
  rgy.x = (cm1 + 2.f*c0 + c1) * 0.125f;
  rgy.y = (c0  + 2.f*c1 + c2) * 0.125f;
  rgy.z = (c1  + 2.f*c2 + c3) * 0.125f;
  rgy.w = (c2  + 2.f*c3 + c4) * 0.125f;
}
__device__ __forceinline__ void p_elem(float4 rgx, float4 rgy, float4 pa, float4 pb,
                                       float4 gg, float4& n1, float4& n2){
#define PE(c) { \
    float mag = __builtin_amdgcn_sqrtf(rgx.c*rgx.c + rgy.c*rgy.c); \
    float inv = __builtin_amdgcn_rcpf(1.f + 0.125f*mag*gg.c); \
    n1.c = (pa.c + 0.125f*rgx.c)*inv; n2.c = (pb.c + 0.125f*rgy.c)*inv; }
  PE(x) PE(y) PE(z) PE(w)
#undef PE
}

// single-row p-update, in place on P1s/P2s, sobel of Rs
template<bool EDGE>
__device__ __forceinline__ void p_phase(const float* Rs, float* P1s, float* P2s,
    const float* gb, int x0, int y0, int tid, int ylo, int nrows){
  int total = nrows * 20;
  for (int i = tid; i < total; i += NTH){
    int cy = i / 20, cx = i - cy*20;
    int x = cx*4 - 8;
    int y = ylo + cy;
    int col = x + 8;                      // column in R coords (stride 80)
    int lo = (col==0) ? 0 : -1;           // clamped reads feed junk cells only
    int ro = (col==76) ? 0 : 4;
    int base = VIDX(y,x);
    RowS Rm1 = load_rowS(Rs, base-VW2, lo, ro);
    RowS R0  = load_rowS(Rs, base,     lo, ro);
    RowS R1  = load_rowS(Rs, base+VW2, lo, ro);
    float4 rgx, rgy;
    sobel_rowsS(Rm1, R0, R1, rgx, rgy);
    int p0 = PIDX(y,x);
    float4 pa = lds4(P1s,p0), pb = lds4(P2s,p0);
    float4 g0 = gld4<EDGE>(gb, y0+y, x0+x);
    float4 n1, n2;
    p_elem(rgx,rgy,pa,pb,g0,n1,n2);
    if (EDGE){
      n1 = mask4(n1, y0+y, x0+x); n2 = mask4(n2, y0+y, x0+x);
    }
    sts4(P1s,p0,n1); sts4(P2s,p0,n2);
  }
}

// v-update (register, skipped when FIRSTR) + r = div(p) - f + v -> Rs
// Each thread owns one fixed chunk (vy, vx); active only inside [ylo, ylo+nrows).
template<bool EDGE, bool FIRSTR>
__device__ __forceinline__ void vr_phase(float* Rs, const float* P1s, const float* P2s,
    float4& vreg, const float* fb, int x0, int y0, int vy, int vx, bool vown,
    int ylo, int nrows){
  if (!vown) return;
  if (vy < ylo || vy >= ylo + nrows) return;
  int y = vy, x = vx;
  int pc = PIDX(y,x);
  float4 m = lds4(P1s,pc);
  float lw = P1s[pc-1], rx = P1s[pc+4];
  float4 up = lds4(P2s,pc-PW2), dn = lds4(P2s,pc+PW2);
  float4 db;
  db.x = (m.y - lw)  + (dn.x - up.x);
  db.y = (m.z - m.x) + (dn.y - up.y);
  db.z = (m.w - m.y) + (dn.z - up.z);
  db.w = (rx  - m.z) + (dn.w - up.w);
  float4 ff = gld4<EDGE>(fb, y0+y, x0+x);
  float4 rv;
  if (!FIRSTR){
    vreg.x = shrink01(vreg.x + db.x); vreg.y = shrink01(vreg.y + db.y);
    vreg.z = shrink01(vreg.z + db.z); vreg.w = shrink01(vreg.w + db.w);
  }
  rv.x = db.x - ff.x + vreg.x; rv.y = db.y - ff.y + vreg.y;
  rv.z = db.z - ff.z + vreg.z; rv.w = db.w - ff.w + vreg.w;
  if (EDGE) rv = mask4(rv, y0+y, x0+x);
  sts4(Rs, VIDX(y,x), rv);
}

template<bool FIRST, bool LAST, bool EDGE>
__device__ __forceinline__ void iter_body4(
    const float* fb, const float* gb,
    const float* p1b, const float* p2b, const float* vb,
    float* p1o, float* p2o, float* vo, float* uo,
    int x0, int y0, int tid,
    float* P1s, float* P2s, float* Rs)
{
  // fixed v-chunk ownership: 48 rows x 20 chunks = 960 threads
  const bool vown = tid < 960;
  const int vcy = tid / 20, vcx = tid - vcy*20;
  const int vy = vcy - 8, vx = vcx*4 - 8;

  // ---- stage p (halo 9, padded to 12) into LDS; v into register
  for (int i = tid; i < 50*22; i += NTH){
    int cy = i / 22, cx = i - cy*22;
    int x = cx*4 - 12, y = cy - 9;
    float4 a, b;
    if (FIRST){ a = f4zero(); b = f4zero(); }
    else {
      int gy = y0+y, gx = x0+x;
      a = gld4<EDGE>(p1b, gy, gx); b = gld4<EDGE>(p2b, gy, gx);
      if (EDGE){ a = mask4(a,gy,gx); b = mask4(b,gy,gx); }
    }
    int idx = PIDX(y,x);
    sts4(P1s, idx, a); sts4(P2s, idx, b);
  }
  float4 vreg = f4zero();
  if (!FIRST && vown){
    int gy = y0+vy, gx = x0+vx;
    vreg = gld4<EDGE>(vb, gy, gx);
    if (EDGE) vreg = mask4(vreg, gy, gx);
  }
  __syncthreads();

  // ---- 4 fused iterations, halo ladder 8->1
  vr_phase<EDGE,true >(Rs,P1s,P2s,vreg,fb,x0,y0,vy,vx,vown,-8,48); __syncthreads();
  p_phase<EDGE>(Rs,P1s,P2s,gb,x0,y0,tid,-7,46);                    __syncthreads();
  vr_phase<EDGE,false>(Rs,P1s,P2s,vreg,fb,x0,y0,vy,vx,vown,-6,44); __syncthreads();
  p_phase<EDGE>(Rs,P1s,P2s,gb,x0,y0,tid,-5,42);                    __syncthreads();
  vr_phase<EDGE,false>(Rs,P1s,P2s,vreg,fb,x0,y0,vy,vx,vown,-4,40); __syncthreads();
  p_phase<EDGE>(Rs,P1s,P2s,gb,x0,y0,tid,-3,38);                    __syncthreads();
  vr_phase<EDGE,false>(Rs,P1s,P2s,vreg,fb,x0,y0,vy,vx,vown,-2,36); __syncthreads();
  p_phase<EDGE>(Rs,P1s,P2s,gb,x0,y0,tid,-1,34);                    __syncthreads();

  // ---- outputs over owned tile: the owning threads have v3 in register
  if (vown && vy >= 0 && vy < TY && vx >= 0 && vx < TX){
    int y = vy, x = vx;
    int pc = PIDX(y,x);
    float4 m = lds4(P1s,pc);
    float lw = P1s[pc-1], rx = P1s[pc+4];
    float4 up = lds4(P2s,pc-PW2), dn = lds4(P2s,pc+PW2);
    float4 dq;
    dq.x = (m.y - lw)  + (dn.x - up.x);
    dq.y = (m.z - m.x) + (dn.y - up.y);
    dq.z = (m.w - m.y) + (dn.z - up.z);
    dq.w = (rx  - m.z) + (dn.w - up.w);
    size_t go = (size_t)(y0+y)*IMW + (x0+x);
    if (LAST){
      float4 ff = gld4<false>(fb, y0+y, x0+x);
      float4 uu;
      uu.x = ff.x - vreg.x - dq.x; uu.y = ff.y - vreg.y - dq.y;
      uu.z = ff.z - vreg.z - dq.z; uu.w = ff.w - vreg.w - dq.w;
      *(float4*)(uo + go) = uu;
    } else {
      float4 m2 = lds4(P2s,pc);
      float4 vn;
      vn.x = shrink01(vreg.x + dq.x); vn.y = shrink01(vreg.y + dq.y);
      vn.z = shrink01(vreg.z + dq.z); vn.w = shrink01(vreg.w + dq.w);
      *(float4*)(p1o + go) = m;
      *(float4*)(p2o + go) = m2;
      *(float4*)(vo  + go) = vn;
    }
  }
}

template<bool FIRST, bool LAST>
__global__ __launch_bounds__(NTH, 8) void iter4_kernel(
    const float* __restrict__ f, const float* __restrict__ ginv,
    const float* __restrict__ p1in, const float* __restrict__ p2in,
    const float* __restrict__ vin,
    float* __restrict__ p1out, float* __restrict__ p2out,
    float* __restrict__ vout, float* __restrict__ uout)
{
  __shared__ alignas(16) float P1s[P_H2*PW2], P2s[P_H2*PW2];
  __shared__ alignas(16) float Rs[V_H2*VW2];

  int phys = blockIdx.x;
  int virt = (phys & 7) * (NBLK/8) + (phys >> 3);   // XCD-chunked, bijective
  int bx = virt & (GXT-1);
  int by = (virt >> 3) & (GYT-1);
  int b  = virt >> 7;
  int x0 = bx*TX, y0 = by*TY;
  size_t boff = (size_t)b * NPIX;
  bool edge = (bx==0) | (bx==GXT-1) | (by==0) | (by==GYT-1);
  int tid = threadIdx.x;

  if (edge)
    iter_body4<FIRST,LAST,true>(f+boff, ginv+boff, p1in+boff, p2in+boff, vin+boff,
        p1out+boff, p2out+boff, vout+boff, uout+boff, x0, y0, tid,
        P1s, P2s, Rs);
  else
    iter_body4<FIRST,LAST,false>(f+boff, ginv+boff, p1in+boff, p2in+boff, vin+boff,
        p1out+boff, p2out+boff, vout+boff, uout+boff, x0, y0, tid,
        P1s, P2s, Rs);
}

// ginv = 1 + gx^2 + gy^2, vectorized: one f4 chunk per thread
__global__ __launch_bounds__(256) void init_kernel(
    const float* __restrict__ f, float* __restrict__ ginv) {
  int i = blockIdx.x * 256 + threadIdx.x;       // 262144 chunks total
  int b = i >> 16; int rem = i & 0xFFFF;
  int gy = rem >> 7; int gx = (rem & 127) * 4;
  const float* fb = f + (size_t)b * NPIX;
  float L[3], R[3]; float4 O[3];
  for (int k = 0; k < 3; ++k){
    int y = gy + k - 1;
    if ((unsigned)y < (unsigned)IMH){
      const float* rp = fb + (size_t)y*IMW + gx;
      O[k] = *(const float4*)rp;
      L[k] = (gx > 0) ? rp[-1] : 0.f;
      R[k] = (gx < IMW-4) ? rp[4] : 0.f;
    } else { O[k] = f4zero(); L[k] = 0.f; R[k] = 0.f; }
  }
  float4 out;
#define GE(c, im1, i0, ip1) { \
    float sx = (i0##_p - i0##_m)*2.f + (im1##_p - im1##_m) + (ip1##_p - ip1##_m); \
    float sy = (ip1##_m - im1##_m) + 2.f*(ip1##_c - im1##_c) + (ip1##_p - im1##_p); \
    out.c = 1.f + sx*sx + sy*sy; }
  { float a_m=L[0], a_c=O[0].x, a_p=O[0].y;
    float b_m=L[1], b_c=O[1].x, b_p=O[1].y;
    float c_m=L[2], c_c=O[2].x, c_p=O[2].y;
    GE(x, a, b, c) }
  { float a_m=O[0].x, a_c=O[0].y, a_p=O[0].z;
    float b_m=O[1].x, b_c=O[1].y, b_p=O[1].z;
    float c_m=O[2].x, c_c=O[2].y, c_p=O[2].z;
    GE(y, a, b, c) }
  { float a_m=O[0].y, a_c=O[0].z, a_p=O[0].w;
    float b_m=O[1].y, b_c=O[1].z, b_p=O[1].w;
    float c_m=O[2].y, c_c=O[2].z, c_p=O[2].w;
    GE(z, a, b, c) }
  { float a_m=O[0].z, a_c=O[0].w, a_p=R[0];
    float b_m=O[1].z, b_c=O[1].w, b_p=R[1];
    float c_m=O[2].z, c_c=O[2].w, c_p=R[2];
    GE(w, a, b, c) }
#undef GE
  *(float4*)(ginv + (size_t)b*NPIX + (size_t)gy*IMW + gx) = out;
}

extern "C" void kernel_launch(void* const* d_in, const int* in_sizes, int n_in,
                              void* d_out, int out_size, void* d_ws, size_t ws_size,
                              hipStream_t stream) {
  const float* f = (const float*)d_in[0];
  float* u = (float*)d_out;
  float* ws = (float*)d_ws;
  const size_t N = (size_t)NB * NPIX;
  float* g   = ws + 0*N;
  float* p1a = ws + 1*N;
  float* p2a = ws + 2*N;
  float* va  = ws + 3*N;
  float* p1b = ws + 4*N;
  float* p2b = ws + 5*N;
  float* vb  = ws + 6*N;

  init_kernel<<<1024, 256, 0, stream>>>(f, g);

  for (int l = 0; l < 25; ++l) {   // 25 x 4 fused = 100 iterations
    const float *pi1, *pi2, *vi;
    float *po1, *po2, *vo;
    if (l & 1) { pi1 = p1b; pi2 = p2b; vi = vb; po1 = p1a; po2 = p2a; vo = va; }
    else       { pi1 = p1a; pi2 = p2a; vi = va; po1 = p1b; po2 = p2b; vo = vb; }
    if (l == 0)
      iter4_kernel<true, false><<<NBLK, NTH, 0, stream>>>(f, g, pi1, pi2, vi, po1, po2, vo, u);
    else if (l == 24)
      iter4_kernel<false, true><<<NBLK, NTH, 0, stream>>>(f, g, pi1, pi2, vi, po1, po2, vo, u);
    else
      iter4_kernel<false, false><<<NBLK, NTH, 0, stream>>>(f, g, pi1, pi2, vi, po1, po2, vo, u);
  }
}

// Round 9
// 394.015 us; speedup vs baseline: 25.3818x; 1.0023x over previous
//
#include <hip/hip_runtime.h>

#define IMH 512
#define IMW 512
#define NB 4
#define NPIX (IMH*IMW)

#define TX 64
#define TY 32
#define GXT 8                 // IMW/TX
#define GYT 16                // IMH/TY
#define NBLK (GXT*GYT*NB)     // 512  == 2 blocks/CU exactly
#define NTH 1024              // 16 waves/block -> 32 waves/CU (max occupancy)

// k=5 fusion, in-place LDS state; v lives in REGISTERS for halo<=8 region:
// ladder: p0@11,v0@10 -> r1@10 -> p1@9 -> {v1,r2}@8 -> p2@7 -> {v2,r3}@6
//         -> p3@5 -> {v3,r4}@4 -> p4@3 -> {v4,r5}@2 -> p5@1 -> out@0
// P (p): y in [-11,43) = 54 rows, x chunks [-12,76) stride 88  (p0->..->p5)
// R (r): y in [-10,42) = 52 rows, same x stride 88             (r1->..->r5)
// vr1 reads v0 straight from global (no v-update); vr2..vr5 use register v
// over the 48x20-chunk ownership region (rows [-8,40), x in [-8,72)).
// Boundary chunks beyond the 20-chunk region go stale for later phases; a
// cell-level validity-narrowing analysis shows stale data only feeds cells
// whose values are never consumed.
// Total LDS = (54*88*2 + 52*88)*4 = 56,320 B -> 2 blocks/CU.
#define PW2 88
#define P_H2 54
#define VW2 88
#define V_H2 52

#define PIDX(y,x) (((y)+11)*PW2 + ((x)+12))
#define VIDX(y,x) (((y)+10)*VW2 + ((x)+12))

__device__ __forceinline__ float4 lds4(const float* p, int i){ return *(const float4*)(p + i); }
__device__ __forceinline__ void  sts4(float* p, int i, float4 v){ *(float4*)(p + i) = v; }
__device__ __forceinline__ float4 f4zero(){ return make_float4(0.f,0.f,0.f,0.f); }
__device__ __forceinline__ float shrink01(float d){
  return d - fminf(fmaxf(d, -0.1f), 0.1f);   // v_med3 idiom
}

template<bool EDGE>
__device__ __forceinline__ float4 gld4(const float* base, int gy, int gx){
  if (EDGE){ gy = min(max(gy,0),IMH-1); gx = min(max(gx,0),IMW-4); }
  return *(const float4*)(base + gy*IMW + gx);
}
__device__ __forceinline__ float4 mask4(float4 v, int gy, int gx){
  if ((unsigned)gy >= (unsigned)IMH) return f4zero();
  v.x = ((unsigned)(gx+0) < (unsigned)IMW) ? v.x : 0.f;
  v.y = ((unsigned)(gx+1) < (unsigned)IMW) ? v.y : 0.f;
  v.z = ((unsigned)(gx+2) < (unsigned)IMW) ? v.z : 0.f;
  v.w = ((unsigned)(gx+3) < (unsigned)IMW) ? v.w : 0.f;
  return v;
}

// row window: only lw (x-1) and rx (x+4) cross the chunk -> b128 + 2x b32
struct RowS { float lw; float4 m; float rx; };
__device__ __forceinline__ RowS load_rowS(const float* A, int base, int lo, int ro){
  RowS q; q.m = lds4(A, base); q.lw = A[base+lo]; q.rx = A[base+ro]; return q;
}
__device__ __forceinline__ float4 dxvS(const RowS& q){
  return make_float4(q.m.y - q.lw, q.m.z - q.m.x, q.m.w - q.m.y, q.rx - q.m.z);
}
__device__ __forceinline__ void sobel_rowsS(const RowS& A, const RowS& B, const RowS& C,
                                            float4& rgx, float4& rgy){
  float4 da = dxvS(A), db = dxvS(B), dc = dxvS(C);
  rgx.x = (da.x + 2.f*db.x + dc.x) * 0.125f;
  rgx.y = (da.y + 2.f*db.y + dc.y) * 0.125f;
  rgx.z = (da.z + 2.f*db.z + dc.z) * 0.125f;
  rgx.w = (da.w + 2.f*db.w + dc.w) * 0.125f;
  float cm1 = C.lw - A.lw;
  float c0 = C.m.x - A.m.x, c1 = C.m.y - A.m.y;
  float c2 = C.m.z - A.m.z, c3 = C.m.w - A.m.w;
  float c4 = C.rx - A.rx;
  rgy.x = (cm1 + 2.f*c0 + c1) * 0.125f;
  rgy.y = (c0  + 2.f*c1 + c2) * 0.125f;
  rgy.z = (c1  + 2.f*c2 + c3) * 0.125f;
  rgy.w = (c2  + 2.f*c3 + c4) * 0.125f;
}
__device__ __forceinline__ void p_elem(float4 rgx, float4 rgy, float4 pa, float4 pb,
                                       float4 gg, float4& n1, float4& n2){
#define PE(c) { \
    float mag = __builtin_amdgcn_sqrtf(rgx.c*rgx.c + rgy.c*rgy.c); \
    float inv = __builtin_amdgcn_rcpf(1.f + 0.125f*mag*gg.c); \
    n1.c = (pa.c + 0.125f*rgx.c)*inv; n2.c = (pb.c + 0.125f*rgy.c)*inv; }
  PE(x) PE(y) PE(z) PE(w)
#undef PE
}

__device__ __forceinline__ float4 divp_at(const float* P1s, const float* P2s, int pc){
  float4 m = lds4(P1s,pc);
  float lw = P1s[pc-1], rx = P1s[pc+4];
  float4 up = lds4(P2s,pc-PW2), dn = lds4(P2s,pc+PW2);
  float4 db;
  db.x = (m.y - lw)  + (dn.x - up.x);
  db.y = (m.z - m.x) + (dn.y - up.y);
  db.z = (m.w - m.y) + (dn.z - up.z);
  db.w = (rx  - m.z) + (dn.w - up.w);
  return db;
}

// iteration-1 r: r1 = div(p0) - f + v0, v0 read from GLOBAL (no v-update).
// Full-width 22 chunks x 52 rows.
template<bool FIRST, bool EDGE>
__device__ __forceinline__ void vr1_phase(float* Rs, const float* P1s, const float* P2s,
    const float* vb, const float* fb, int x0, int y0, int tid){
  for (int i = tid; i < 52*22; i += NTH){
    int cy = i / 22, cx = i - cy*22;
    int x = cx*4 - 12, y = cy - 10;
    float4 db = divp_at(P1s, P2s, PIDX(y,x));
    float4 ff = gld4<EDGE>(fb, y0+y, x0+x);
    float4 vv = f4zero();
    if (!FIRST){
      vv = gld4<EDGE>(vb, y0+y, x0+x);
      if (EDGE) vv = mask4(vv, y0+y, x0+x);
    }
    float4 rv;
    rv.x = db.x - ff.x + vv.x; rv.y = db.y - ff.y + vv.y;
    rv.z = db.z - ff.z + vv.z; rv.w = db.w - ff.w + vv.w;
    if (EDGE) rv = mask4(rv, y0+y, x0+x);
    sts4(Rs, VIDX(y,x), rv);
  }
}

// single-row p-update, in place on P1s/P2s, sobel of Rs.
// CPR = chunks per row (22 for p1, 20 for p2..p5), XBASE = first chunk x.
template<bool EDGE, int CPR, int XBASE>
__device__ __forceinline__ void p_phase(const float* Rs, float* P1s, float* P2s,
    const float* gb, int x0, int y0, int tid, int ylo, int nrows){
  int total = nrows * CPR;
  for (int i = tid; i < total; i += NTH){
    int cy = i / CPR, cx = i - cy*CPR;
    int x = cx*4 + XBASE;
    int y = ylo + cy;
    int col = x + 12;                     // column in R coords (stride 88)
    int lo = (col==0) ? 0 : -1;           // clamped reads feed junk cells only
    int ro = (col==84) ? 0 : 4;
    int base = VIDX(y,x);
    RowS Rm1 = load_rowS(Rs, base-VW2, lo, ro);
    RowS R0  = load_rowS(Rs, base,     lo, ro);
    RowS R1  = load_rowS(Rs, base+VW2, lo, ro);
    float4 rgx, rgy;
    sobel_rowsS(Rm1, R0, R1, rgx, rgy);
    int p0 = PIDX(y,x);
    float4 pa = lds4(P1s,p0), pb = lds4(P2s,p0);
    float4 g0 = gld4<EDGE>(gb, y0+y, x0+x);
    float4 n1, n2;
    p_elem(rgx,rgy,pa,pb,g0,n1,n2);
    if (EDGE){
      n1 = mask4(n1, y0+y, x0+x); n2 = mask4(n2, y0+y, x0+x);
    }
    sts4(P1s,p0,n1); sts4(P2s,p0,n2);
  }
}

// register-v update + r = div(p) - f + v_new -> Rs, on owned chunk only.
template<bool EDGE>
__device__ __forceinline__ void vr_phase(float* Rs, const float* P1s, const float* P2s,
    float4& vreg, const float* fb, int x0, int y0, int vy, int vx, bool vown,
    int ylo, int nrows){
  if (!vown) return;
  if (vy < ylo || vy >= ylo + nrows) return;
  int y = vy, x = vx;
  float4 db = divp_at(P1s, P2s, PIDX(y,x));
  float4 ff = gld4<EDGE>(fb, y0+y, x0+x);
  vreg.x = shrink01(vreg.x + db.x); vreg.y = shrink01(vreg.y + db.y);
  vreg.z = shrink01(vreg.z + db.z); vreg.w = shrink01(vreg.w + db.w);
  float4 rv;
  rv.x = db.x - ff.x + vreg.x; rv.y = db.y - ff.y + vreg.y;
  rv.z = db.z - ff.z + vreg.z; rv.w = db.w - ff.w + vreg.w;
  if (EDGE) rv = mask4(rv, y0+y, x0+x);
  sts4(Rs, VIDX(y,x), rv);
}

template<bool FIRST, bool LAST, bool EDGE>
__device__ __forceinline__ void iter_body5(
    const float* fb, const float* gb,
    const float* p1b, const float* p2b, const float* vb,
    float* p1o, float* p2o, float* vo, float* uo,
    int x0, int y0, int tid,
    float* P1s, float* P2s, float* Rs)
{
  // fixed v-chunk ownership: rows [-8,40) x chunks [-8,72) = 48x20 = 960
  const bool vown = tid < 960;
  const int vcy = tid / 20, vcx = tid - vcy*20;
  const int vy = vcy - 8, vx = vcx*4 - 8;

  // ---- stage p (halo 11, padded to 12) into LDS; v into register
  for (int i = tid; i < 54*22; i += NTH){
    int cy = i / 22, cx = i - cy*22;
    int x = cx*4 - 12, y = cy - 11;
    float4 a, b;
    if (FIRST){ a = f4zero(); b = f4zero(); }
    else {
      int gy = y0+y, gx = x0+x;
      a = gld4<EDGE>(p1b, gy, gx); b = gld4<EDGE>(p2b, gy, gx);
      if (EDGE){ a = mask4(a,gy,gx); b = mask4(b,gy,gx); }
    }
    int idx = PIDX(y,x);
    sts4(P1s, idx, a); sts4(P2s, idx, b);
  }
  float4 vreg = f4zero();
  if (!FIRST && vown){
    int gy = y0+vy, gx = x0+vx;
    vreg = gld4<EDGE>(vb, gy, gx);
    if (EDGE) vreg = mask4(vreg, gy, gx);
  }
  __syncthreads();

  // ---- 5 fused iterations
  vr1_phase<FIRST,EDGE>(Rs,P1s,P2s,vb,fb,x0,y0,tid);                __syncthreads();
  p_phase<EDGE,22,-12>(Rs,P1s,P2s,gb,x0,y0,tid,-9,50);              __syncthreads();
  vr_phase<EDGE>(Rs,P1s,P2s,vreg,fb,x0,y0,vy,vx,vown,-8,48);        __syncthreads();
  p_phase<EDGE,20,-8>(Rs,P1s,P2s,gb,x0,y0,tid,-7,46);               __syncthreads();
  vr_phase<EDGE>(Rs,P1s,P2s,vreg,fb,x0,y0,vy,vx,vown,-6,44);        __syncthreads();
  p_phase<EDGE,20,-8>(Rs,P1s,P2s,gb,x0,y0,tid,-5,42);               __syncthreads();
  vr_phase<EDGE>(Rs,P1s,P2s,vreg,fb,x0,y0,vy,vx,vown,-4,40);        __syncthreads();
  p_phase<EDGE,20,-8>(Rs,P1s,P2s,gb,x0,y0,tid,-3,38);               __syncthreads();
  vr_phase<EDGE>(Rs,P1s,P2s,vreg,fb,x0,y0,vy,vx,vown,-2,36);        __syncthreads();
  p_phase<EDGE,20,-8>(Rs,P1s,P2s,gb,x0,y0,tid,-1,34);               __syncthreads();

  // ---- outputs over owned tile: the owning threads have v4 in register
  if (vown && vy >= 0 && vy < TY && vx >= 0 && vx < TX){
    int y = vy, x = vx;
    int pc = PIDX(y,x);
    float4 dq = divp_at(P1s, P2s, pc);
    size_t go = (size_t)(y0+y)*IMW + (x0+x);
    if (LAST){
      float4 ff = gld4<false>(fb, y0+y, x0+x);
      float4 uu;
      uu.x = ff.x - vreg.x - dq.x; uu.y = ff.y - vreg.y - dq.y;
      uu.z = ff.z - vreg.z - dq.z; uu.w = ff.w - vreg.w - dq.w;
      *(float4*)(uo + go) = uu;
    } else {
      float4 m  = lds4(P1s,pc);
      float4 m2 = lds4(P2s,pc);
      float4 vn;
      vn.x = shrink01(vreg.x + dq.x); vn.y = shrink01(vreg.y + dq.y);
      vn.z = shrink01(vreg.z + dq.z); vn.w = shrink01(vreg.w + dq.w);
      *(float4*)(p1o + go) = m;
      *(float4*)(p2o + go) = m2;
      *(float4*)(vo  + go) = vn;
    }
  }
}

template<bool FIRST, bool LAST>
__global__ __launch_bounds__(NTH, 8) void iter5_kernel(
    const float* __restrict__ f, const float* __restrict__ ginv,
    const float* __restrict__ p1in, const float* __restrict__ p2in,
    const float* __restrict__ vin,
    float* __restrict__ p1out, float* __restrict__ p2out,
    float* __restrict__ vout, float* __restrict__ uout)
{
  __shared__ alignas(16) float P1s[P_H2*PW2], P2s[P_H2*PW2];
  __shared__ alignas(16) float Rs[V_H2*VW2];

  int phys = blockIdx.x;
  int virt = (phys & 7) * (NBLK/8) + (phys >> 3);   // XCD-chunked, bijective
  int bx = virt & (GXT-1);
  int by = (virt >> 3) & (GYT-1);
  int b  = virt >> 7;
  int x0 = bx*TX, y0 = by*TY;
  size_t boff = (size_t)b * NPIX;
  bool edge = (bx==0) | (bx==GXT-1) | (by==0) | (by==GYT-1);
  int tid = threadIdx.x;

  if (edge)
    iter_body5<FIRST,LAST,true>(f+boff, ginv+boff, p1in+boff, p2in+boff, vin+boff,
        p1out+boff, p2out+boff, vout+boff, uout+boff, x0, y0, tid,
        P1s, P2s, Rs);
  else
    iter_body5<FIRST,LAST,false>(f+boff, ginv+boff, p1in+boff, p2in+boff, vin+boff,
        p1out+boff, p2out+boff, vout+boff, uout+boff, x0, y0, tid,
        P1s, P2s, Rs);
}

// ginv = 1 + gx^2 + gy^2, vectorized: one f4 chunk per thread
__global__ __launch_bounds__(256) void init_kernel(
    const float* __restrict__ f, float* __restrict__ ginv) {
  int i = blockIdx.x * 256 + threadIdx.x;       // 262144 chunks total
  int b = i >> 16; int rem = i & 0xFFFF;
  int gy = rem >> 7; int gx = (rem & 127) * 4;
  const float* fb = f + (size_t)b * NPIX;
  float L[3], R[3]; float4 O[3];
  for (int k = 0; k < 3; ++k){
    int y = gy + k - 1;
    if ((unsigned)y < (unsigned)IMH){
      const float* rp = fb + (size_t)y*IMW + gx;
      O[k] = *(const float4*)rp;
      L[k] = (gx > 0) ? rp[-1] : 0.f;
      R[k] = (gx < IMW-4) ? rp[4] : 0.f;
    } else { O[k] = f4zero(); L[k] = 0.f; R[k] = 0.f; }
  }
  float4 out;
#define GE(c, im1, i0, ip1) { \
    float sx = (i0##_p - i0##_m)*2.f + (im1##_p - im1##_m) + (ip1##_p - ip1##_m); \
    float sy = (ip1##_m - im1##_m) + 2.f*(ip1##_c - im1##_c) + (ip1##_p - im1##_p); \
    out.c = 1.f + sx*sx + sy*sy; }
  { float a_m=L[0], a_c=O[0].x, a_p=O[0].y;
    float b_m=L[1], b_c=O[1].x, b_p=O[1].y;
    float c_m=L[2], c_c=O[2].x, c_p=O[2].y;
    GE(x, a, b, c) }
  { float a_m=O[0].x, a_c=O[0].y, a_p=O[0].z;
    float b_m=O[1].x, b_c=O[1].y, b_p=O[1].z;
    float c_m=O[2].x, c_c=O[2].y, c_p=O[2].z;
    GE(y, a, b, c) }
  { float a_m=O[0].y, a_c=O[0].z, a_p=O[0].w;
    float b_m=O[1].y, b_c=O[1].z, b_p=O[1].w;
    float c_m=O[2].y, c_c=O[2].z, c_p=O[2].w;
    GE(z, a, b, c) }
  { float a_m=O[0].z, a_c=O[0].w, a_p=R[0];
    float b_m=O[1].z, b_c=O[1].w, b_p=R[1];
    float c_m=O[2].z, c_c=O[2].w, c_p=R[2];
    GE(w, a, b, c) }
#undef GE
  *(float4*)(ginv + (size_t)b*NPIX + (size_t)gy*IMW + gx) = out;
}

extern "C" void kernel_launch(void* const* d_in, const int* in_sizes, int n_in,
                              void* d_out, int out_size, void* d_ws, size_t ws_size,
                              hipStream_t stream) {
  const float* f = (const float*)d_in[0];
  float* u = (float*)d_out;
  float* ws = (float*)d_ws;
  const size_t N = (size_t)NB * NPIX;
  float* g   = ws + 0*N;
  float* p1a = ws + 1*N;
  float* p2a = ws + 2*N;
  float* va  = ws + 3*N;
  float* p1b = ws + 4*N;
  float* p2b = ws + 5*N;
  float* vb  = ws + 6*N;

  init_kernel<<<1024, 256, 0, stream>>>(f, g);

  for (int l = 0; l < 20; ++l) {   // 20 x 5 fused = 100 iterations
    const float *pi1, *pi2, *vi;
    float *po1, *po2, *vo;
    if (l & 1) { pi1 = p1b; pi2 = p2b; vi = vb; po1 = p1a; po2 = p2a; vo = va; }
    else       { pi1 = p1a; pi2 = p2a; vi = va; po1 = p1b; po2 = p2b; vo = vb; }
    if (l == 0)
      iter5_kernel<true, false><<<NBLK, NTH, 0, stream>>>(f, g, pi1, pi2, vi, po1, po2, vo, u);
    else if (l == 19)
      iter5_kernel<false, true><<<NBLK, NTH, 0, stream>>>(f, g, pi1, pi2, vi, po1, po2, vo, u);
    else
      iter5_kernel<false, false><<<NBLK, NTH, 0, stream>>>(f, g, pi1, pi2, vi, po1, po2, vo, u);
  }
}